// Round 7
// baseline (1533.041 us; speedup 1.0000x reference)
//
#include <hip/hip_runtime.h>
#include <hip/hip_bf16.h>

typedef __attribute__((ext_vector_type(8))) short bf16x8;
typedef __attribute__((ext_vector_type(4))) short bf16x4;
typedef __attribute__((ext_vector_type(4))) float f32x4;

#define DEV static __device__ __forceinline__

constexpr int Bc = 4, NQc = 900, Hc = 8, Sc = 21760;
constexpr int M1 = Bc * NQc;           // 3600
constexpr int NQT = (NQc + 63) / 64;   // 15 key tiles of 64
constexpr int QT16 = (NQc + 15) / 16;  // 57 query tiles of 16
constexpr int QKo = Bc * Hc * 960 * 32;  // 983040: size of one [b][h][960][32] buf
constexpr int QKV_BLOCKS = 113 * 3;    // 339 qkv blocks in the fused launch

DEV short f2bf(float f) {
  union { __hip_bfloat16 h; short s; } u;
  u.h = __float2bfloat16(f);
  return u.s;
}
DEV float bf2f(short s) {
  union { short s; __hip_bfloat16 h; } u;
  u.s = s;
  return __bfloat162float(u.h);
}

// ---------------------------------------------------------------------------
// Pack W[K][N] f32 -> k-tiled bf16 [K/32][N][32]
DEV void pack_body(const float* W, short* Wt, int K, int N, int t) {
  int n = t % N;
  int k4 = (t / N) * 4;
  bf16x4 o;
  o[0] = f2bf(W[(size_t)(k4 + 0) * N + n]);
  o[1] = f2bf(W[(size_t)(k4 + 1) * N + n]);
  o[2] = f2bf(W[(size_t)(k4 + 2) * N + n]);
  o[3] = f2bf(W[(size_t)(k4 + 3) * N + n]);
  *(bf16x4*)&Wt[((size_t)(k4 >> 5) * N + n) * 32 + (k4 & 31)] = o;
}

__global__ __launch_bounds__(256) void pack_all_k(
    const float* w0, short* t0, const float* w1, short* t1,
    const float* w2, short* t2, const float* w3, short* t3,
    const float* w4, short* t4, const float* w5, short* t5) {
  int t = blockIdx.x * 256 + threadIdx.x;
  if (t < 49152) pack_body(w0, t0, 256, 768, t);
  else if (t < 65536) pack_body(w1, t1, 256, 256, t - 49152);
  else if (t < 81920) pack_body(w2, t2, 256, 256, t - 65536);
  else if (t < 98304) pack_body(w3, t3, 256, 256, t - 81920);
  else if (t < 163840) pack_body(w4, t4, 256, 1024, t - 98304);
  else pack_body(w5, t5, 1024, 256, t - 163840);
}

// ---------------------------------------------------------------------------
// Unified MT x 256N bf16 MFMA GEMM body, K-step 32, distance-2 reg prefetch.
// MODE 0: f32 out (+ACT relu)
// MODE 3: LN epilogue (N=256): Cv = LN(resid + A@W + b)*g + beta [+ out2=+qpos]
// MODE 4: qkv: bn0 -> qbf (scaled bf16 [bh][960][32]), bn1 -> kbf (same),
//         bn2 -> vtbf (bf16 [bh][15][32ch][64key]); q,k add A2.
template <int MODE, int ACT, int MT>
DEV void gemmv_body(
    const float* __restrict__ A, const float* __restrict__ A2,
    const short* __restrict__ Wt, const float* __restrict__ bias,
    void* __restrict__ Cv, int M, int N, int K,
    const float* __restrict__ g, const float* __restrict__ beta,
    const float* __restrict__ resid, const float* __restrict__ qpos,
    float* __restrict__ out2, int bid, short* As, short* Ws) {
  constexpr int IT = MT / 16;
  const int nb = N >> 8;
  const int mb = bid / nb, bn = bid - mb * nb;
  const int tid = threadIdx.x;
  const int lane = tid & 63, wave = tid >> 6;
  const int l16 = lane & 15, quad = lane >> 4;
  const int sr = (MT == 64) ? (tid >> 2) : (tid >> 3);
  const int sk = (MT == 64) ? ((tid & 3) * 8) : ((tid & 7) * 4);
  const int arow = mb * MT + sr;
  const bool aval = arow < M;
  const bool useA2 = (MODE == 4) ? (bn < 2) : (A2 != nullptr);
  const float* ap = A + (size_t)arow * K + sk;
  const float* ap2 = (A2 ? A2 : A) + (size_t)arow * K + sk;
  const short* wp = Wt + (size_t)(bn * 256 + tid) * 32;
  const size_t wstep = (size_t)N * 32;
  const int KT = K >> 5;

  f32x4 acc[IT][4] = {};
  float4 pa0[2] = {}, pa1[2] = {};
  bf16x8 pw[2][4];

  auto loadA = [&](int s, int it) {
    if (aval) {
      const float* p = ap + it * 32;
      pa0[s] = *(const float4*)p;
      if constexpr (MT == 64) pa1[s] = *(const float4*)(p + 4);
      if (useA2) {
        const float* p2 = ap2 + it * 32;
        float4 q0 = *(const float4*)p2;
        pa0[s].x += q0.x; pa0[s].y += q0.y; pa0[s].z += q0.z; pa0[s].w += q0.w;
        if constexpr (MT == 64) {
          float4 q1 = *(const float4*)(p2 + 4);
          pa1[s].x += q1.x; pa1[s].y += q1.y; pa1[s].z += q1.z; pa1[s].w += q1.w;
        }
      }
    }
  };
  auto loadW = [&](int s, int it) {
    const short* p = wp + (size_t)it * wstep;
    pw[s][0] = *(const bf16x8*)(p + 0);
    pw[s][1] = *(const bf16x8*)(p + 8);
    pw[s][2] = *(const bf16x8*)(p + 16);
    pw[s][3] = *(const bf16x8*)(p + 24);
  };
  auto stage = [&](int s) {
    if constexpr (MT == 64) {
      bf16x8 t;
      t[0] = f2bf(pa0[s].x); t[1] = f2bf(pa0[s].y); t[2] = f2bf(pa0[s].z); t[3] = f2bf(pa0[s].w);
      t[4] = f2bf(pa1[s].x); t[5] = f2bf(pa1[s].y); t[6] = f2bf(pa1[s].z); t[7] = f2bf(pa1[s].w);
      *(bf16x8*)&As[sr * 40 + sk] = t;
    } else {
      bf16x4 t;
      t[0] = f2bf(pa0[s].x); t[1] = f2bf(pa0[s].y); t[2] = f2bf(pa0[s].z); t[3] = f2bf(pa0[s].w);
      *(bf16x4*)&As[sr * 40 + sk] = t;
    }
    short* wd = &Ws[tid * 40];
    *(bf16x8*)(wd + 0) = pw[s][0];
    *(bf16x8*)(wd + 8) = pw[s][1];
    *(bf16x8*)(wd + 16) = pw[s][2];
    *(bf16x8*)(wd + 24) = pw[s][3];
  };
  auto compute = [&]() {
    bf16x8 af[IT], bfr[4];
#pragma unroll
    for (int i = 0; i < IT; i++)
      af[i] = *(const bf16x8*)&As[(i * 16 + l16) * 40 + quad * 8];
#pragma unroll
    for (int j = 0; j < 4; j++)
      bfr[j] = *(const bf16x8*)&Ws[(wave * 64 + j * 16 + l16) * 40 + quad * 8];
#pragma unroll
    for (int i = 0; i < IT; i++)
#pragma unroll
      for (int j = 0; j < 4; j++)
        acc[i][j] = __builtin_amdgcn_mfma_f32_16x16x32_bf16(af[i], bfr[j], acc[i][j], 0, 0, 0);
  };

  loadA(0, 0); loadW(0, 0);
  loadA(1, 1); loadW(1, 1);
  for (int it = 0; it < KT; it += 2) {
    stage(0);
    __syncthreads();
    if (it + 2 < KT) { loadA(0, it + 2); loadW(0, it + 2); }
    compute();
    __syncthreads();
    stage(1);
    __syncthreads();
    if (it + 3 < KT) { loadA(1, it + 3); loadW(1, it + 3); }
    compute();
    __syncthreads();
  }

  // ---- epilogues ----
  if constexpr (MODE == 4) {
    short* base = (short*)Cv;
#pragma unroll
    for (int i = 0; i < IT; i++)
#pragma unroll
      for (int r = 0; r < 4; r++) {
        const int m = mb * MT + i * 16 + quad * 4 + r;
        if (m >= M) continue;
        const int b = m / NQc, q = m - b * NQc;
#pragma unroll
        for (int j = 0; j < 4; j++) {
          const int cl = wave * 64 + j * 16 + l16;
          const float v = acc[i][j][r] + bias[bn * 256 + cl];
          const int h = cl >> 5, ch = cl & 31;
          if (bn == 0) {
            base[((size_t)(b * 8 + h) * 960 + q) * 32 + ch] =
                f2bf(v * 0.17677669529663687f);
          } else if (bn == 1) {
            base[QKo + ((size_t)(b * 8 + h) * 960 + q) * 32 + ch] = f2bf(v);
          } else {
            base[2 * QKo + ((((size_t)(b * 8 + h) * 15 + (q >> 6)) * 32 + ch) * 64 + (q & 63))] = f2bf(v);
          }
        }
      }
  } else if constexpr (MODE == 0) {
#pragma unroll
    for (int i = 0; i < IT; i++)
#pragma unroll
      for (int j = 0; j < 4; j++) {
        const int cl = wave * 64 + j * 16 + l16;
        const int col = bn * 256 + cl;
        const float bb = bias[col];
#pragma unroll
        for (int r = 0; r < 4; r++) {
          const int m = mb * MT + i * 16 + quad * 4 + r;
          if (m < M) {
            float v = acc[i][j][r] + bb;
            if (ACT == 1) v = fmaxf(v, 0.f);
            ((float*)Cv)[(size_t)m * N + col] = v;
          }
        }
      }
  } else {  // MODE 3: fused LayerNorm epilogue (N==256)
#pragma unroll
    for (int j = 0; j < 4; j++) {
      const int cl = wave * 64 + j * 16 + l16;
      const float bb = bias[cl];
#pragma unroll
      for (int i = 0; i < IT; i++)
#pragma unroll
        for (int r = 0; r < 4; r++) {
          const int m = mb * MT + i * 16 + quad * 4 + r;
          const float rs = (m < M) ? resid[(size_t)m * 256 + cl] : 0.f;
          acc[i][j][r] += bb + rs;
        }
    }
    float2* pr = (float2*)As;
#pragma unroll
    for (int i = 0; i < IT; i++)
#pragma unroll
      for (int r = 0; r < 4; r++) {
        float s = 0.f, q = 0.f;
#pragma unroll
        for (int j = 0; j < 4; j++) {
          s += acc[i][j][r];
          q += acc[i][j][r] * acc[i][j][r];
        }
#pragma unroll
        for (int d = 1; d < 16; d <<= 1) {
          s += __shfl_xor(s, d);
          q += __shfl_xor(q, d);
        }
        if (l16 == 0) pr[(i * 16 + quad * 4 + r) * 4 + wave] = make_float2(s, q);
      }
    __syncthreads();
#pragma unroll
    for (int i = 0; i < IT; i++)
#pragma unroll
      for (int r = 0; r < 4; r++) {
        const int ml = i * 16 + quad * 4 + r;
        float2 p0 = pr[ml * 4 + 0], p1 = pr[ml * 4 + 1];
        float2 p2 = pr[ml * 4 + 2], p3 = pr[ml * 4 + 3];
        const float sum = p0.x + p1.x + p2.x + p3.x;
        const float sq = p0.y + p1.y + p2.y + p3.y;
        const float mean = sum * (1.f / 256.f);
        const float var = sq * (1.f / 256.f) - mean * mean;
        const float rstd = rsqrtf(var + 1e-5f);
        const int m = mb * MT + ml;
        if (m < M) {
#pragma unroll
          for (int j = 0; j < 4; j++) {
            const int cl = wave * 64 + j * 16 + l16;
            const float o = (acc[i][j][r] - mean) * rstd * g[cl] + beta[cl];
            ((float*)Cv)[(size_t)m * 256 + cl] = o;
            if (out2) out2[(size_t)m * 256 + cl] = o + qpos[(size_t)m * 256 + cl];
          }
        }
      }
  }
}

template <int MODE, int ACT, int MT>
__global__ __launch_bounds__(256) void gemmv_k(
    const float* __restrict__ A, const float* __restrict__ A2,
    const short* __restrict__ Wt, const float* __restrict__ bias,
    void* __restrict__ Cv, float* __restrict__ C2, int M, int N, int K,
    const unsigned char* __restrict__ rowmask, const float* __restrict__ g,
    const float* __restrict__ beta, const float* __restrict__ resid,
    const float* __restrict__ qpos, float* __restrict__ out2) {
  __shared__ short As[MT * 40];
  __shared__ short Ws[256 * 40];
  gemmv_body<MODE, ACT, MT>(A, A2, Wt, bias, Cv, M, N, K, g, beta, resid,
                            qpos, out2, blockIdx.x, As, Ws);
}

// ---------------------------------------------------------------------------
// Value projection GEMM body, v6 (verified round 6): full-N blocks, A and B
// read once at every cache level. A via global_load_lds with pre-swizzled
// source + XOR read; B direct global->reg distance-1 dbuf. One block per
// 64-row tile (1360 tiles).
DEV void val_body(const float* __restrict__ A, const short* __restrict__ Wt,
                  const float* __restrict__ bias, short* __restrict__ Cv,
                  int M, const unsigned char* __restrict__ rowmask, int mb,
                  float* As /* [2][64*32] floats */) {
  const int tid = threadIdx.x;
  const int lane = tid & 63, wave = tid >> 6;
  const int l16 = lane & 15, quad = lane >> 4;

  // B fragment: col = wave*64 + j*16 + l16, k-tile it, sub-k quad*8
  const short* wp = Wt + (size_t)(wave * 64 + l16) * 32 + quad * 8;

  // A staging source (pre-swizzled chunk so linear DMA + XOR read = identity)
  const int srow = lane >> 3;
  const int schunk = ((lane & 7) ^ srow) * 4;  // swizzled k-chunk (floats)
  const float* abase = A + (size_t)(mb * 64 + wave * 8 + srow) * 256 + schunk;

  f32x4 acc[4][4] = {};
  bf16x8 pb[2][4];

  auto stage = [&](int buf, int it) {
#pragma unroll
    for (int call = 0; call < 2; ++call) {
      const float* src = abase + (size_t)call * (32 * 256) + it * 32;
      float* dst = &As[buf * 2048 + (call * 32 + wave * 8) * 32];
      __builtin_amdgcn_global_load_lds(
          (const __attribute__((address_space(1))) void*)src,
          (__attribute__((address_space(3))) void*)dst, 16, 0, 0);
    }
  };
  auto loadB = [&](int s, int it) {
#pragma unroll
    for (int j = 0; j < 4; j++)
      pb[s][j] = *(const bf16x8*)(wp + (size_t)(it * 256 + j * 16) * 32);
  };
  auto compute = [&](int cur) {
    bf16x8 af[4];
#pragma unroll
    for (int i = 0; i < 4; i++) {
      const int row = i * 16 + l16;
      const int cb = row & 7;
      const float4 a0 =
          *(const float4*)&As[cur * 2048 + row * 32 + (((quad * 2) ^ cb) << 2)];
      const float4 a1 = *(const float4*)&As[cur * 2048 + row * 32 +
                                            (((quad * 2 + 1) ^ cb) << 2)];
      af[i][0] = f2bf(a0.x); af[i][1] = f2bf(a0.y);
      af[i][2] = f2bf(a0.z); af[i][3] = f2bf(a0.w);
      af[i][4] = f2bf(a1.x); af[i][5] = f2bf(a1.y);
      af[i][6] = f2bf(a1.z); af[i][7] = f2bf(a1.w);
    }
#pragma unroll
    for (int i = 0; i < 4; i++)
#pragma unroll
      for (int j = 0; j < 4; j++)
        acc[i][j] = __builtin_amdgcn_mfma_f32_16x16x32_bf16(af[i], pb[cur][j],
                                                            acc[i][j], 0, 0, 0);
  };

  stage(0, 0);
  loadB(0, 0);
  __syncthreads();  // As[0] + pb[0] ready
  for (int it = 0; it < 8; ++it) {
    const int cur = it & 1;
    if (it + 1 < 8) { stage(cur ^ 1, it + 1); loadB(cur ^ 1, it + 1); }
    compute(cur);     // ds_read + MFMA while next-tile loads fly
    __syncthreads();  // drains stage/loadB(it+1); all waves done with As[cur]
  }

  float bb[4];
#pragma unroll
  for (int j = 0; j < 4; j++) bb[j] = bias[wave * 64 + j * 16 + l16];
#pragma unroll
  for (int i = 0; i < 4; i++)
#pragma unroll
    for (int r = 0; r < 4; r++) {
      const int m = mb * 64 + i * 16 + quad * 4 + r;
      const bool mk = rowmask[m] != 0;
#pragma unroll
      for (int j = 0; j < 4; j++) {
        const int cl = wave * 64 + j * 16 + l16;
        float v = acc[i][j][r] + bb[j];
        if (mk) v = 0.f;
        Cv[(size_t)m * 256 + cl] = f2bf(v);
      }
    }
}

// ---------------------------------------------------------------------------
// Fused qkv + value-projection launch (round-7): qkv (339 blocks, underfills
// the 256-CU machine) and val (1360 latency-bound blocks, independent of the
// whole attention arm) co-scheduled in ONE kernel -> val's ~52 us hides
// under / alongside qkv instead of occupying its own serial slot. Shared-LDS
// pool = max(qkv 23040 B, val 16384 B).
__global__ __launch_bounds__(256, 3) void qkv_val_k(
    const float* __restrict__ tgt, const float* __restrict__ qpos,
    const short* __restrict__ inT, const float* __restrict__ in_b,
    short* __restrict__ qbf, const float* __restrict__ mem,
    const short* __restrict__ vT, const float* __restrict__ v_b,
    short* __restrict__ valBf, const unsigned char* __restrict__ mask) {
  __shared__ __align__(16) char pool[23040];
  if (blockIdx.x < QKV_BLOCKS) {
    gemmv_body<4, 0, 32>(tgt, qpos, inT, in_b, qbf, M1, 768, 256, nullptr,
                         nullptr, nullptr, nullptr, nullptr, blockIdx.x,
                         (short*)pool, (short*)(pool + 2560));
  } else {
    val_body(mem, vT, v_b, valBf, Bc * Sc, mask, blockIdx.x - QKV_BLOCKS,
             (float*)pool);
  }
}

// ---------------------------------------------------------------------------
// Exact fp32 GEMM body (off/aw: sampler-amplified precision path)
DEV void gemm32_body(const float* __restrict__ A, const float* __restrict__ W,
                     const float* __restrict__ bias, float* __restrict__ C,
                     int M, int N, int K, int bid) {
  __shared__ float Asf[16][64];
  __shared__ float Bsf[16][68];
  const int nb = N >> 6;
  const int bm = bid / nb, bn = bid % nb;
  const int tid = threadIdx.x;
  const int tm = tid >> 4, tn = tid & 15;
  float acc[4][4] = {};

  for (int k0 = 0; k0 < K; k0 += 16) {
    {
      const int m = tid >> 2, kk = (tid & 3) * 4;
      const int row = bm * 64 + m;
      float4 v = (row < M) ? *(const float4*)(A + (size_t)row * K + k0 + kk)
                           : make_float4(0.f, 0.f, 0.f, 0.f);
      Asf[kk + 0][m] = v.x; Asf[kk + 1][m] = v.y;
      Asf[kk + 2][m] = v.z; Asf[kk + 3][m] = v.w;
    }
    {
      const int kk = tid >> 4, n = (tid & 15) * 4;
      float4 v = *(const float4*)(W + (size_t)(k0 + kk) * N + bn * 64 + n);
      *(float4*)&Bsf[kk][n] = v;
    }
    __syncthreads();
#pragma unroll
    for (int kk = 0; kk < 16; kk++) {
      float a[4], b[4];
#pragma unroll
      for (int i = 0; i < 4; i++) a[i] = Asf[kk][tm * 4 + i];
#pragma unroll
      for (int j = 0; j < 4; j++) b[j] = Bsf[kk][tn * 4 + j];
#pragma unroll
      for (int i = 0; i < 4; i++)
#pragma unroll
        for (int j = 0; j < 4; j++) acc[i][j] = fmaf(a[i], b[j], acc[i][j]);
    }
    __syncthreads();
  }
#pragma unroll
  for (int i = 0; i < 4; i++) {
    const int row = bm * 64 + tm * 4 + i;
    if (row >= M) continue;
#pragma unroll
    for (int j = 0; j < 4; j++) {
      const int col = bn * 64 + tn * 4 + j;
      C[(size_t)row * N + col] = acc[i][j] + bias[col];
    }
  }
}

__global__ __launch_bounds__(256) void gemm32_offaw_k(
    const float* __restrict__ query, const float* __restrict__ off_w,
    const float* __restrict__ off_b, float* __restrict__ offb,
    const float* __restrict__ aw_w, const float* __restrict__ aw_b,
    float* __restrict__ awlin) {
  if (blockIdx.x < 228)
    gemm32_body(query, off_w, off_b, offb, M1, 256, 256, blockIdx.x);
  else
    gemm32_body(query, aw_w, aw_b, awlin, M1, 128, 256, blockIdx.x - 228);
}

// ---------------------------------------------------------------------------
// Flash attention from pre-packed bf16 buffers. Block = (b,h,16 queries),
// 2 waves split key tiles even/odd. Hot loop: coalesced bf16x8 global loads
// (Q,K from [bh][960][32], V^T from [bh][15][32][64]) straight into MFMA —
// no f2bf, no V staging, no barriers. Single merge barrier at end.
__global__ __launch_bounds__(128) void attn_k(const short* __restrict__ qbf,
                                              const short* __restrict__ kbf,
                                              const short* __restrict__ vtbf,
                                              float* __restrict__ sa) {
  __shared__ short Pb[2][16 * 72];
  __shared__ float Om[2][16][32];
  __shared__ float Ml[2][16][2];
  const int bid = blockIdx.x;
  const int qt = bid % QT16, bh = bid / QT16;
  const int tid = threadIdx.x, lane = tid & 63, wave = tid >> 6;
  const int l16 = lane & 15, quad = lane >> 4;

  const int q_local = min(qt * 16 + l16, NQc - 1);
  const bf16x8 qf = *(const bf16x8*)&qbf[((size_t)bh * 960 + q_local) * 32 + quad * 8];
  const short* kb = kbf + (size_t)bh * 960 * 32;
  const short* vb = vtbf + (size_t)bh * 15 * 32 * 64;

  f32x4 o0 = {}, o1 = {};
  float mrun[4] = {-1e30f, -1e30f, -1e30f, -1e30f};
  float lrun[4] = {0.f, 0.f, 0.f, 0.f};
  short* pw = Pb[wave];

  for (int kt = wave; kt < NQT; kt += 2) {
    const int k0 = kt * 64;
    f32x4 s[4];
#pragma unroll
    for (int st = 0; st < 4; st++) {
      const int key = k0 + st * 16 + l16;
      const bf16x8 kf = *(const bf16x8*)&kb[(size_t)key * 32 + quad * 8];
      f32x4 z = {};
      s[st] = __builtin_amdgcn_mfma_f32_16x16x32_bf16(qf, kf, z, 0, 0, 0);
      if (key >= NQc) { s[st][0] = -1e30f; s[st][1] = -1e30f; s[st][2] = -1e30f; s[st][3] = -1e30f; }
    }
    float mnew[4], alpha[4];
#pragma unroll
    for (int r = 0; r < 4; r++) {
      float mx = fmaxf(fmaxf(s[0][r], s[1][r]), fmaxf(s[2][r], s[3][r]));
#pragma unroll
      for (int d = 1; d < 16; d <<= 1) mx = fmaxf(mx, __shfl_xor(mx, d));
      mnew[r] = fmaxf(mrun[r], mx);
      alpha[r] = __expf(mrun[r] - mnew[r]);
      mrun[r] = mnew[r];
    }
    float tsum[4] = {0.f, 0.f, 0.f, 0.f};
#pragma unroll
    for (int st = 0; st < 4; st++)
#pragma unroll
      for (int r = 0; r < 4; r++) {
        float p = __expf(s[st][r] - mnew[r]);
        s[st][r] = p;
        tsum[r] += p;
      }
#pragma unroll
    for (int r = 0; r < 4; r++) {
      float t = tsum[r];
#pragma unroll
      for (int d = 1; d < 16; d <<= 1) t += __shfl_xor(t, d);
      lrun[r] = lrun[r] * alpha[r] + t;
      o0[r] *= alpha[r];
      o1[r] *= alpha[r];
    }
    // P: C-layout -> A-layout via per-wave LDS (wave-local, no barrier)
#pragma unroll
    for (int st = 0; st < 4; st++)
#pragma unroll
      for (int r = 0; r < 4; r++)
        pw[(quad * 4 + r) * 72 + st * 16 + l16] = f2bf(s[st][r]);
    const short* vt = vb + kt * (32 * 64);
#pragma unroll
    for (int c = 0; c < 2; c++) {
      bf16x8 pf = *(const bf16x8*)&pw[l16 * 72 + c * 32 + quad * 8];
      bf16x8 vf0 = *(const bf16x8*)&vt[(size_t)l16 * 64 + c * 32 + quad * 8];
      bf16x8 vf1 = *(const bf16x8*)&vt[(size_t)(16 + l16) * 64 + c * 32 + quad * 8];
      o0 = __builtin_amdgcn_mfma_f32_16x16x32_bf16(pf, vf0, o0, 0, 0, 0);
      o1 = __builtin_amdgcn_mfma_f32_16x16x32_bf16(pf, vf1, o1, 0, 0, 0);
    }
  }
#pragma unroll
  for (int r = 0; r < 4; r++) {
    Om[wave][quad * 4 + r][l16] = o0[r];
    Om[wave][quad * 4 + r][16 + l16] = o1[r];
  }
  if (l16 == 0) {
#pragma unroll
    for (int r = 0; r < 4; r++) {
      Ml[wave][quad * 4 + r][0] = mrun[r];
      Ml[wave][quad * 4 + r][1] = lrun[r];
    }
  }
  __syncthreads();
  {
    const int q = tid >> 3;
    const int c4 = (tid & 7) * 4;
    const float m0 = Ml[0][q][0], m1 = Ml[1][q][0];
    const float M = fmaxf(m0, m1);
    const float a0 = __expf(m0 - M), a1 = __expf(m1 - M);
    const float lsum = a0 * Ml[0][q][1] + a1 * Ml[1][q][1];
    const int qg = qt * 16 + q;
    if (qg < NQc) {
      const float inv = 1.f / lsum;
      float4 o;
      o.x = (a0 * Om[0][q][c4 + 0] + a1 * Om[1][q][c4 + 0]) * inv;
      o.y = (a0 * Om[0][q][c4 + 1] + a1 * Om[1][q][c4 + 1]) * inv;
      o.z = (a0 * Om[0][q][c4 + 2] + a1 * Om[1][q][c4 + 2]) * inv;
      o.w = (a0 * Om[0][q][c4 + 3] + a1 * Om[1][q][c4 + 3]) * inv;
      const int b = bh >> 3, h = bh & 7;
      *(float4*)&sa[(size_t)(b * NQc + qg) * 256 + h * 32 + c4] = o;
    }
  }
}

// ---------------------------------------------------------------------------
__global__ __launch_bounds__(256) void sample_k(
    const float* __restrict__ awlin, const float* __restrict__ off,
    const float* __restrict__ refp, const short* __restrict__ value,
    float* __restrict__ accout) {
  const int wid = blockIdx.x * 4 + (threadIdx.x >> 6);
  const int lane = threadIdx.x & 63;
  const int bq = wid >> 3, h = wid & 7;
  const int b = bq / NQc;
  const int l16 = lane & 15;

  float wraw = awlin[(size_t)bq * 128 + h * 16 + l16];
  float mx = wraw;
#pragma unroll
  for (int d = 1; d < 16; d <<= 1) mx = fmaxf(mx, __shfl_xor(mx, d));
  float e = __expf(wraw - mx), ssum = e;
#pragma unroll
  for (int d = 1; d < 16; d <<= 1) ssum += __shfl_xor(ssum, d);
  const float wnorm = e / ssum;

  const int ch = lane & 31, sub = lane >> 5;
  float facc = 0.f;
#pragma unroll
  for (int it = 0; it < 8; it++) {
    const int pt = it * 2 + sub;
    const float w = __shfl(wnorm, pt);
    const int l = pt >> 2;
    const int W = 128 >> l;
    const int start = (l == 0) ? 0 : (l == 1) ? 16384 : (l == 2) ? 20480 : 21504;
    const float offx = off[(size_t)bq * 256 + h * 32 + pt * 2];
    const float offy = off[(size_t)bq * 256 + h * 32 + pt * 2 + 1];
    const float rx = refp[(size_t)bq * 8 + l * 2];
    const float ry = refp[(size_t)bq * 8 + l * 2 + 1];
    const float x = rx * (float)W + offx - 0.5f;
    const float y = ry * (float)W + offy - 0.5f;
    const float x0f = floorf(x), y0f = floorf(y);
    const float wx = x - x0f, wy = y - y0f;
    const int x0 = (int)x0f, y0 = (int)y0f;
    const short* vbp = value + ((size_t)b * Sc + start) * 256 + h * 32 + ch;
#pragma unroll
    for (int c4 = 0; c4 < 4; c4++) {
      const int dx = c4 & 1, dy = c4 >> 1;
      const int xi = x0 + dx, yi = y0 + dy;
      const bool valid = (xi >= 0) && (xi < W) && (yi >= 0) && (yi < W);
      const int xc = min(max(xi, 0), W - 1);
      const int yc = min(max(yi, 0), W - 1);
      const float gvv = bf2f(vbp[(size_t)(yc * W + xc) * 256]);
      const float ww = (dx ? wx : 1.f - wx) * (dy ? wy : 1.f - wy);
      facc += valid ? w * ww * gvv : 0.f;
    }
  }
  facc += __shfl_xor(facc, 32);
  if (lane < 32) accout[(size_t)bq * 256 + h * 32 + ch] = facc;
}

// ---------------------------------------------------------------------------
extern "C" void kernel_launch(void* const* d_in, const int* in_sizes, int n_in,
                              void* d_out, int out_size, void* d_ws,
                              size_t ws_size, hipStream_t stream) {
  const float* tgt = (const float*)d_in[0];
  const float* query_pos = (const float*)d_in[1];
  const float* refp = (const float*)d_in[2];
  const float* memory = (const float*)d_in[3];
  const float* in_proj_w = (const float*)d_in[4];
  const float* in_proj_b = (const float*)d_in[5];
  const float* out_proj_w = (const float*)d_in[6];
  const float* out_proj_b = (const float*)d_in[7];
  const float* ln1_g = (const float*)d_in[8];
  const float* ln1_b = (const float*)d_in[9];
  const float* ln2_g = (const float*)d_in[10];
  const float* ln2_b = (const float*)d_in[11];
  const float* ln3_g = (const float*)d_in[12];
  const float* ln3_b = (const float*)d_in[13];
  const float* vproj_w = (const float*)d_in[14];
  const float* vproj_b = (const float*)d_in[15];
  const float* off_w = (const float*)d_in[16];
  const float* off_b = (const float*)d_in[17];
  const float* aw_w = (const float*)d_in[18];
  const float* aw_b = (const float*)d_in[19];
  const float* oproj_w = (const float*)d_in[20];
  const float* oproj_b = (const float*)d_in[21];
  const float* lin1_w = (const float*)d_in[22];
  const float* lin1_b = (const float*)d_in[23];
  const float* lin2_w = (const float*)d_in[24];
  const float* lin2_b = (const float*)d_in[25];
  const unsigned char* mem_mask = (const unsigned char*)d_in[27];
  float* out = (float*)d_out;

  float* ws = (float*)d_ws;
  short* qbf = (short*)(ws + 921600);  // qbf|kbf|vtbf: 3*983040 shorts
  float* sa = ws + 3686400;
  float* tgt2 = ws + 5529600;
  float* query = ws + 6451200;
  float* offb = ws + 7372800;
  float* awlin = ws + 8294400;
  float* accb = ws + 8755200;
  float* tgt3 = ws + 9676800;
  float* ff1 = ws + 10598400;     // [3600][1024]
  short* valueBf = (short*)(ws + 14284800);  // 22282240 shorts
  short* wbase = valueBf + 22282240;
  short* inT = wbase + 0;         // [8][768][32]
  short* outT = wbase + 196608;
  short* vT = wbase + 262144;
  short* oT = wbase + 327680;
  short* lin1T = wbase + 393216;  // [8][1024][32]
  short* lin2T = wbase + 655360;  // [32][256][32]

  pack_all_k<<<896, 256, 0, stream>>>(in_proj_w, inT, out_proj_w, outT,
                                      vproj_w, vT, oproj_w, oT,
                                      lin1_w, lin1T, lin2_w, lin2T);

  // fused q|k|v projection AND value projection (independent GEMMs
  // co-scheduled: 339 qkv blocks + 1360 val blocks fill the machine)
  qkv_val_k<<<QKV_BLOCKS + 1360, 256, 0, stream>>>(
      tgt, query_pos, inT, in_proj_b, qbf, memory, vT, vproj_b, valueBf,
      mem_mask);
  attn_k<<<Bc * Hc * QT16, 128, 0, stream>>>(qbf, qbf + QKo, qbf + 2 * QKo, sa);
  // out_proj + residual + LN2, and query = tgt2 + query_pos
  gemmv_k<3, 0, 32><<<113, 256, 0, stream>>>(
      sa, nullptr, outT, out_proj_b, tgt2, nullptr, M1, 256, 256,
      nullptr, ln2_g, ln2_b, tgt, query_pos, query);
  // off + aw (exact fp32: sampler-amplified path)
  gemm32_offaw_k<<<342, 256, 0, stream>>>(query, off_w, off_b, offb, aw_w, aw_b, awlin);
  sample_k<<<Bc * NQc * Hc / 4, 256, 0, stream>>>(awlin, offb, refp, valueBf, accb);
  // oproj + residual + LN1
  gemmv_k<3, 0, 32><<<113, 256, 0, stream>>>(
      accb, nullptr, oT, oproj_b, tgt3, nullptr, M1, 256, 256,
      nullptr, ln1_g, ln1_b, tgt2, nullptr, nullptr);
  // FFN
  gemmv_k<0, 1, 64><<<57 * 4, 256, 0, stream>>>(
      tgt3, nullptr, lin1T, lin1_b, ff1, nullptr, M1, 1024, 256,
      nullptr, nullptr, nullptr, nullptr, nullptr, nullptr);
  gemmv_k<3, 0, 32><<<113, 256, 0, stream>>>(
      ff1, nullptr, lin2T, lin2_b, out, nullptr, M1, 256, 1024,
      nullptr, ln3_g, ln3_b, tgt3, nullptr, nullptr);
}

// Round 8
// 414.943 us; speedup vs baseline: 3.6946x; 3.6946x over previous
//
#include <hip/hip_runtime.h>
#include <hip/hip_bf16.h>

typedef __attribute__((ext_vector_type(8))) short bf16x8;
typedef __attribute__((ext_vector_type(4))) short bf16x4;
typedef __attribute__((ext_vector_type(4))) float f32x4;

#define DEV static __device__ __forceinline__

constexpr int Bc = 4, NQc = 900, Hc = 8, Sc = 21760;
constexpr int M1 = Bc * NQc;           // 3600
constexpr int NQT = (NQc + 63) / 64;   // 15 key tiles of 64
constexpr int QT16 = (NQc + 15) / 16;  // 57 query tiles of 16
constexpr int QKo = Bc * Hc * 960 * 32;  // 983040: size of one [b][h][960][32] buf

DEV short f2bf(float f) {
  union { __hip_bfloat16 h; short s; } u;
  u.h = __float2bfloat16(f);
  return u.s;
}
DEV float bf2f(short s) {
  union { short s; __hip_bfloat16 h; } u;
  u.s = s;
  return __bfloat162float(u.h);
}

// ---------------------------------------------------------------------------
// Pack W[K][N] f32 -> k-tiled bf16 [K/32][N][32]
DEV void pack_body(const float* W, short* Wt, int K, int N, int t) {
  int n = t % N;
  int k4 = (t / N) * 4;
  bf16x4 o;
  o[0] = f2bf(W[(size_t)(k4 + 0) * N + n]);
  o[1] = f2bf(W[(size_t)(k4 + 1) * N + n]);
  o[2] = f2bf(W[(size_t)(k4 + 2) * N + n]);
  o[3] = f2bf(W[(size_t)(k4 + 3) * N + n]);
  *(bf16x4*)&Wt[((size_t)(k4 >> 5) * N + n) * 32 + (k4 & 31)] = o;
}

__global__ __launch_bounds__(256) void pack_all_k(
    const float* w0, short* t0, const float* w1, short* t1,
    const float* w2, short* t2, const float* w3, short* t3,
    const float* w4, short* t4, const float* w5, short* t5) {
  int t = blockIdx.x * 256 + threadIdx.x;
  if (t < 49152) pack_body(w0, t0, 256, 768, t);
  else if (t < 65536) pack_body(w1, t1, 256, 256, t - 49152);
  else if (t < 81920) pack_body(w2, t2, 256, 256, t - 65536);
  else if (t < 98304) pack_body(w3, t3, 256, 256, t - 81920);
  else if (t < 163840) pack_body(w4, t4, 256, 1024, t - 98304);
  else pack_body(w5, t5, 1024, 256, t - 163840);
}

// ---------------------------------------------------------------------------
// Unified MT x 256N bf16 MFMA GEMM, K-step 32, distance-2 register prefetch.
// MODE 0: f32 out (+ACT relu)
// MODE 3: LN epilogue (N=256): Cv = LN(resid + A@W + b)*g + beta [+ out2=+qpos]
// MODE 4: qkv: bn0 -> qbf (scaled bf16 [bh][960][32]), bn1 -> kbf (same),
//         bn2 -> vtbf (bf16 [bh][15][32ch][64key]); q,k add A2.
template <int MODE, int ACT, int MT>
__global__ __launch_bounds__(256) void gemmv_k(
    const float* __restrict__ A, const float* __restrict__ A2,
    const short* __restrict__ Wt, const float* __restrict__ bias,
    void* __restrict__ Cv, float* __restrict__ C2, int M, int N, int K,
    const unsigned char* __restrict__ rowmask, const float* __restrict__ g,
    const float* __restrict__ beta, const float* __restrict__ resid,
    const float* __restrict__ qpos, float* __restrict__ out2) {
  constexpr int IT = MT / 16;
  __shared__ short As[MT * 40];
  __shared__ short Ws[256 * 40];
  const int nb = N >> 8;
  const int mb = blockIdx.x / nb, bn = blockIdx.x - mb * nb;
  const int tid = threadIdx.x;
  const int lane = tid & 63, wave = tid >> 6;
  const int l16 = lane & 15, quad = lane >> 4;
  const int sr = (MT == 64) ? (tid >> 2) : (tid >> 3);
  const int sk = (MT == 64) ? ((tid & 3) * 8) : ((tid & 7) * 4);
  const int arow = mb * MT + sr;
  const bool aval = arow < M;
  const bool useA2 = (MODE == 4) ? (bn < 2) : (A2 != nullptr);
  const float* ap = A + (size_t)arow * K + sk;
  const float* ap2 = (A2 ? A2 : A) + (size_t)arow * K + sk;
  const short* wp = Wt + (size_t)(bn * 256 + tid) * 32;
  const size_t wstep = (size_t)N * 32;
  const int KT = K >> 5;

  f32x4 acc[IT][4] = {};
  float4 pa0[2] = {}, pa1[2] = {};
  bf16x8 pw[2][4];

  auto loadA = [&](int s, int it) {
    if (aval) {
      const float* p = ap + it * 32;
      pa0[s] = *(const float4*)p;
      if constexpr (MT == 64) pa1[s] = *(const float4*)(p + 4);
      if (useA2) {
        const float* p2 = ap2 + it * 32;
        float4 q0 = *(const float4*)p2;
        pa0[s].x += q0.x; pa0[s].y += q0.y; pa0[s].z += q0.z; pa0[s].w += q0.w;
        if constexpr (MT == 64) {
          float4 q1 = *(const float4*)(p2 + 4);
          pa1[s].x += q1.x; pa1[s].y += q1.y; pa1[s].z += q1.z; pa1[s].w += q1.w;
        }
      }
    }
  };
  auto loadW = [&](int s, int it) {
    const short* p = wp + (size_t)it * wstep;
    pw[s][0] = *(const bf16x8*)(p + 0);
    pw[s][1] = *(const bf16x8*)(p + 8);
    pw[s][2] = *(const bf16x8*)(p + 16);
    pw[s][3] = *(const bf16x8*)(p + 24);
  };
  auto stage = [&](int s) {
    if constexpr (MT == 64) {
      bf16x8 t;
      t[0] = f2bf(pa0[s].x); t[1] = f2bf(pa0[s].y); t[2] = f2bf(pa0[s].z); t[3] = f2bf(pa0[s].w);
      t[4] = f2bf(pa1[s].x); t[5] = f2bf(pa1[s].y); t[6] = f2bf(pa1[s].z); t[7] = f2bf(pa1[s].w);
      *(bf16x8*)&As[sr * 40 + sk] = t;
    } else {
      bf16x4 t;
      t[0] = f2bf(pa0[s].x); t[1] = f2bf(pa0[s].y); t[2] = f2bf(pa0[s].z); t[3] = f2bf(pa0[s].w);
      *(bf16x4*)&As[sr * 40 + sk] = t;
    }
    short* wd = &Ws[tid * 40];
    *(bf16x8*)(wd + 0) = pw[s][0];
    *(bf16x8*)(wd + 8) = pw[s][1];
    *(bf16x8*)(wd + 16) = pw[s][2];
    *(bf16x8*)(wd + 24) = pw[s][3];
  };
  auto compute = [&]() {
    bf16x8 af[IT], bfr[4];
#pragma unroll
    for (int i = 0; i < IT; i++)
      af[i] = *(const bf16x8*)&As[(i * 16 + l16) * 40 + quad * 8];
#pragma unroll
    for (int j = 0; j < 4; j++)
      bfr[j] = *(const bf16x8*)&Ws[(wave * 64 + j * 16 + l16) * 40 + quad * 8];
#pragma unroll
    for (int i = 0; i < IT; i++)
#pragma unroll
      for (int j = 0; j < 4; j++)
        acc[i][j] = __builtin_amdgcn_mfma_f32_16x16x32_bf16(af[i], bfr[j], acc[i][j], 0, 0, 0);
  };

  loadA(0, 0); loadW(0, 0);
  loadA(1, 1); loadW(1, 1);
  for (int it = 0; it < KT; it += 2) {
    stage(0);
    __syncthreads();
    if (it + 2 < KT) { loadA(0, it + 2); loadW(0, it + 2); }
    compute();
    __syncthreads();
    stage(1);
    __syncthreads();
    if (it + 3 < KT) { loadA(1, it + 3); loadW(1, it + 3); }
    compute();
    __syncthreads();
  }

  // ---- epilogues ----
  if constexpr (MODE == 4) {
    short* base = (short*)Cv;
#pragma unroll
    for (int i = 0; i < IT; i++)
#pragma unroll
      for (int r = 0; r < 4; r++) {
        const int m = mb * MT + i * 16 + quad * 4 + r;
        if (m >= M) continue;
        const int b = m / NQc, q = m - b * NQc;
#pragma unroll
        for (int j = 0; j < 4; j++) {
          const int cl = wave * 64 + j * 16 + l16;
          const float v = acc[i][j][r] + bias[bn * 256 + cl];
          const int h = cl >> 5, ch = cl & 31;
          if (bn == 0) {
            base[((size_t)(b * 8 + h) * 960 + q) * 32 + ch] =
                f2bf(v * 0.17677669529663687f);
          } else if (bn == 1) {
            base[QKo + ((size_t)(b * 8 + h) * 960 + q) * 32 + ch] = f2bf(v);
          } else {
            base[2 * QKo + ((((size_t)(b * 8 + h) * 15 + (q >> 6)) * 32 + ch) * 64 + (q & 63))] = f2bf(v);
          }
        }
      }
  } else if constexpr (MODE == 0) {
#pragma unroll
    for (int i = 0; i < IT; i++)
#pragma unroll
      for (int j = 0; j < 4; j++) {
        const int cl = wave * 64 + j * 16 + l16;
        const int col = bn * 256 + cl;
        const float bb = bias[col];
#pragma unroll
        for (int r = 0; r < 4; r++) {
          const int m = mb * MT + i * 16 + quad * 4 + r;
          if (m < M) {
            float v = acc[i][j][r] + bb;
            if (ACT == 1) v = fmaxf(v, 0.f);
            ((float*)Cv)[(size_t)m * N + col] = v;
          }
        }
      }
  } else {  // MODE 3: fused LayerNorm epilogue (N==256)
#pragma unroll
    for (int j = 0; j < 4; j++) {
      const int cl = wave * 64 + j * 16 + l16;
      const float bb = bias[cl];
#pragma unroll
      for (int i = 0; i < IT; i++)
#pragma unroll
        for (int r = 0; r < 4; r++) {
          const int m = mb * MT + i * 16 + quad * 4 + r;
          const float rs = (m < M) ? resid[(size_t)m * 256 + cl] : 0.f;
          acc[i][j][r] += bb + rs;
        }
    }
    float2* pr = (float2*)As;
#pragma unroll
    for (int i = 0; i < IT; i++)
#pragma unroll
      for (int r = 0; r < 4; r++) {
        float s = 0.f, q = 0.f;
#pragma unroll
        for (int j = 0; j < 4; j++) {
          s += acc[i][j][r];
          q += acc[i][j][r] * acc[i][j][r];
        }
#pragma unroll
        for (int d = 1; d < 16; d <<= 1) {
          s += __shfl_xor(s, d);
          q += __shfl_xor(q, d);
        }
        if (l16 == 0) pr[(i * 16 + quad * 4 + r) * 4 + wave] = make_float2(s, q);
      }
    __syncthreads();
#pragma unroll
    for (int i = 0; i < IT; i++)
#pragma unroll
      for (int r = 0; r < 4; r++) {
        const int ml = i * 16 + quad * 4 + r;
        float2 p0 = pr[ml * 4 + 0], p1 = pr[ml * 4 + 1];
        float2 p2 = pr[ml * 4 + 2], p3 = pr[ml * 4 + 3];
        const float sum = p0.x + p1.x + p2.x + p3.x;
        const float sq = p0.y + p1.y + p2.y + p3.y;
        const float mean = sum * (1.f / 256.f);
        const float var = sq * (1.f / 256.f) - mean * mean;
        const float rstd = rsqrtf(var + 1e-5f);
        const int m = mb * MT + ml;
        if (m < M) {
#pragma unroll
          for (int j = 0; j < 4; j++) {
            const int cl = wave * 64 + j * 16 + l16;
            const float o = (acc[i][j][r] - mean) * rstd * g[cl] + beta[cl];
            ((float*)Cv)[(size_t)m * 256 + cl] = o;
            if (out2) out2[(size_t)m * 256 + cl] = o + qpos[(size_t)m * 256 + cl];
          }
        }
      }
  }
}

// ---------------------------------------------------------------------------
// Value projection GEMM, v8: round-6 structure (full-N blocks, A and B read
// once at every cache level — the verified traffic-optimal form) with the
// row-tile halved 64->32 (grid 2720) for TLP: LDS 8 KB, acc 32 VGPR ->
// __launch_bounds__(256,6) = 6 blocks/CU = 24 waves/CU resident (v6 ran at
// 22% occupancy / 3 blocks/CU). Round-7 lesson applied: standalone kernel,
// __shared__ declared in kernel scope (no pooled-LDS pointer passing).
__global__ __launch_bounds__(256, 6) void gemm_val_k(
    const float* __restrict__ A, const short* __restrict__ Wt,
    const float* __restrict__ bias, short* __restrict__ Cv, int M,
    const unsigned char* __restrict__ rowmask) {
  __shared__ float As[2][32 * 32];  // 8 KB
  const int mb = blockIdx.x;
  const int tid = threadIdx.x;
  const int lane = tid & 63, wave = tid >> 6;
  const int l16 = lane & 15, quad = lane >> 4;

  // B fragment: col = wave*64 + j*16 + l16, k-tile it, sub-k quad*8
  const short* wp = Wt + (size_t)(wave * 64 + l16) * 32 + quad * 8;

  // A staging source (pre-swizzled chunk so linear DMA + XOR read = identity)
  const int srow = lane >> 3;                  // row within the wave's 8 rows
  const int schunk = ((lane & 7) ^ srow) * 4;  // swizzled k-chunk (floats)
  const float* abase = A + (size_t)(mb * 32 + wave * 8 + srow) * 256 + schunk;

  f32x4 acc[2][4] = {};
  bf16x8 pb[2][4];

  auto stage = [&](int buf, int it) {
    const float* src = abase + it * 32;
    float* dst = &As[buf][wave * 8 * 32];  // wave-uniform; lanes fill lane*16B
    __builtin_amdgcn_global_load_lds(
        (const __attribute__((address_space(1))) void*)src,
        (__attribute__((address_space(3))) void*)dst, 16, 0, 0);
  };
  auto loadB = [&](int s, int it) {
#pragma unroll
    for (int j = 0; j < 4; j++)
      pb[s][j] = *(const bf16x8*)(wp + (size_t)(it * 256 + j * 16) * 32);
  };
  auto compute = [&](int cur) {
    bf16x8 af[2];
#pragma unroll
    for (int i = 0; i < 2; i++) {
      const int row = i * 16 + l16;
      const int cb = row & 7;
      const float4 a0 =
          *(const float4*)&As[cur][row * 32 + (((quad * 2) ^ cb) << 2)];
      const float4 a1 =
          *(const float4*)&As[cur][row * 32 + (((quad * 2 + 1) ^ cb) << 2)];
      af[i][0] = f2bf(a0.x); af[i][1] = f2bf(a0.y);
      af[i][2] = f2bf(a0.z); af[i][3] = f2bf(a0.w);
      af[i][4] = f2bf(a1.x); af[i][5] = f2bf(a1.y);
      af[i][6] = f2bf(a1.z); af[i][7] = f2bf(a1.w);
    }
#pragma unroll
    for (int i = 0; i < 2; i++)
#pragma unroll
      for (int j = 0; j < 4; j++)
        acc[i][j] = __builtin_amdgcn_mfma_f32_16x16x32_bf16(af[i], pb[cur][j],
                                                            acc[i][j], 0, 0, 0);
  };

  stage(0, 0);
  loadB(0, 0);
  __syncthreads();  // As[0] + pb[0] ready
  for (int it = 0; it < 8; ++it) {
    const int cur = it & 1;
    if (it + 1 < 8) { stage(cur ^ 1, it + 1); loadB(cur ^ 1, it + 1); }
    compute(cur);     // ds_read + MFMA while next-tile loads fly
    __syncthreads();  // drains stage/loadB(it+1); all waves done with As[cur]
  }

  float bb[4];
#pragma unroll
  for (int j = 0; j < 4; j++) bb[j] = bias[wave * 64 + j * 16 + l16];
#pragma unroll
  for (int i = 0; i < 2; i++)
#pragma unroll
    for (int r = 0; r < 4; r++) {
      const int m = mb * 32 + i * 16 + quad * 4 + r;
      const bool mk = rowmask[m] != 0;
#pragma unroll
      for (int j = 0; j < 4; j++) {
        const int cl = wave * 64 + j * 16 + l16;
        float v = acc[i][j][r] + bb[j];
        if (mk) v = 0.f;
        Cv[(size_t)m * 256 + cl] = f2bf(v);
      }
    }
}

// ---------------------------------------------------------------------------
// Exact fp32 GEMM body (off/aw: sampler-amplified precision path)
DEV void gemm32_body(const float* __restrict__ A, const float* __restrict__ W,
                     const float* __restrict__ bias, float* __restrict__ C,
                     int M, int N, int K, int bid) {
  __shared__ float Asf[16][64];
  __shared__ float Bsf[16][68];
  const int nb = N >> 6;
  const int bm = bid / nb, bn = bid % nb;
  const int tid = threadIdx.x;
  const int tm = tid >> 4, tn = tid & 15;
  float acc[4][4] = {};

  for (int k0 = 0; k0 < K; k0 += 16) {
    {
      const int m = tid >> 2, kk = (tid & 3) * 4;
      const int row = bm * 64 + m;
      float4 v = (row < M) ? *(const float4*)(A + (size_t)row * K + k0 + kk)
                           : make_float4(0.f, 0.f, 0.f, 0.f);
      Asf[kk + 0][m] = v.x; Asf[kk + 1][m] = v.y;
      Asf[kk + 2][m] = v.z; Asf[kk + 3][m] = v.w;
    }
    {
      const int kk = tid >> 4, n = (tid & 15) * 4;
      float4 v = *(const float4*)(W + (size_t)(k0 + kk) * N + bn * 64 + n);
      *(float4*)&Bsf[kk][n] = v;
    }
    __syncthreads();
#pragma unroll
    for (int kk = 0; kk < 16; kk++) {
      float a[4], b[4];
#pragma unroll
      for (int i = 0; i < 4; i++) a[i] = Asf[kk][tm * 4 + i];
#pragma unroll
      for (int j = 0; j < 4; j++) b[j] = Bsf[kk][tn * 4 + j];
#pragma unroll
      for (int i = 0; i < 4; i++)
#pragma unroll
        for (int j = 0; j < 4; j++) acc[i][j] = fmaf(a[i], b[j], acc[i][j]);
    }
    __syncthreads();
  }
#pragma unroll
  for (int i = 0; i < 4; i++) {
    const int row = bm * 64 + tm * 4 + i;
    if (row >= M) continue;
#pragma unroll
    for (int j = 0; j < 4; j++) {
      const int col = bn * 64 + tn * 4 + j;
      C[(size_t)row * N + col] = acc[i][j] + bias[col];
    }
  }
}

__global__ __launch_bounds__(256) void gemm32_offaw_k(
    const float* __restrict__ query, const float* __restrict__ off_w,
    const float* __restrict__ off_b, float* __restrict__ offb,
    const float* __restrict__ aw_w, const float* __restrict__ aw_b,
    float* __restrict__ awlin) {
  if (blockIdx.x < 228)
    gemm32_body(query, off_w, off_b, offb, M1, 256, 256, blockIdx.x);
  else
    gemm32_body(query, aw_w, aw_b, awlin, M1, 128, 256, blockIdx.x - 228);
}

// ---------------------------------------------------------------------------
// Flash attention from pre-packed bf16 buffers. Block = (b,h,16 queries),
// 2 waves split key tiles even/odd. Hot loop: coalesced bf16x8 global loads
// (Q,K from [bh][960][32], V^T from [bh][15][32][64]) straight into MFMA —
// no f2bf, no V staging, no barriers. Single merge barrier at end.
__global__ __launch_bounds__(128) void attn_k(const short* __restrict__ qbf,
                                              const short* __restrict__ kbf,
                                              const short* __restrict__ vtbf,
                                              float* __restrict__ sa) {
  __shared__ short Pb[2][16 * 72];
  __shared__ float Om[2][16][32];
  __shared__ float Ml[2][16][2];
  const int bid = blockIdx.x;
  const int qt = bid % QT16, bh = bid / QT16;
  const int tid = threadIdx.x, lane = tid & 63, wave = tid >> 6;
  const int l16 = lane & 15, quad = lane >> 4;

  const int q_local = min(qt * 16 + l16, NQc - 1);
  const bf16x8 qf = *(const bf16x8*)&qbf[((size_t)bh * 960 + q_local) * 32 + quad * 8];
  const short* kb = kbf + (size_t)bh * 960 * 32;
  const short* vb = vtbf + (size_t)bh * 15 * 32 * 64;

  f32x4 o0 = {}, o1 = {};
  float mrun[4] = {-1e30f, -1e30f, -1e30f, -1e30f};
  float lrun[4] = {0.f, 0.f, 0.f, 0.f};
  short* pw = Pb[wave];

  for (int kt = wave; kt < NQT; kt += 2) {
    const int k0 = kt * 64;
    f32x4 s[4];
#pragma unroll
    for (int st = 0; st < 4; st++) {
      const int key = k0 + st * 16 + l16;
      const bf16x8 kf = *(const bf16x8*)&kb[(size_t)key * 32 + quad * 8];
      f32x4 z = {};
      s[st] = __builtin_amdgcn_mfma_f32_16x16x32_bf16(qf, kf, z, 0, 0, 0);
      if (key >= NQc) { s[st][0] = -1e30f; s[st][1] = -1e30f; s[st][2] = -1e30f; s[st][3] = -1e30f; }
    }
    float mnew[4], alpha[4];
#pragma unroll
    for (int r = 0; r < 4; r++) {
      float mx = fmaxf(fmaxf(s[0][r], s[1][r]), fmaxf(s[2][r], s[3][r]));
#pragma unroll
      for (int d = 1; d < 16; d <<= 1) mx = fmaxf(mx, __shfl_xor(mx, d));
      mnew[r] = fmaxf(mrun[r], mx);
      alpha[r] = __expf(mrun[r] - mnew[r]);
      mrun[r] = mnew[r];
    }
    float tsum[4] = {0.f, 0.f, 0.f, 0.f};
#pragma unroll
    for (int st = 0; st < 4; st++)
#pragma unroll
      for (int r = 0; r < 4; r++) {
        float p = __expf(s[st][r] - mnew[r]);
        s[st][r] = p;
        tsum[r] += p;
      }
#pragma unroll
    for (int r = 0; r < 4; r++) {
      float t = tsum[r];
#pragma unroll
      for (int d = 1; d < 16; d <<= 1) t += __shfl_xor(t, d);
      lrun[r] = lrun[r] * alpha[r] + t;
      o0[r] *= alpha[r];
      o1[r] *= alpha[r];
    }
    // P: C-layout -> A-layout via per-wave LDS (wave-local, no barrier)
#pragma unroll
    for (int st = 0; st < 4; st++)
#pragma unroll
      for (int r = 0; r < 4; r++)
        pw[(quad * 4 + r) * 72 + st * 16 + l16] = f2bf(s[st][r]);
    const short* vt = vb + kt * (32 * 64);
#pragma unroll
    for (int c = 0; c < 2; c++) {
      bf16x8 pf = *(const bf16x8*)&pw[l16 * 72 + c * 32 + quad * 8];
      bf16x8 vf0 = *(const bf16x8*)&vt[(size_t)l16 * 64 + c * 32 + quad * 8];
      bf16x8 vf1 = *(const bf16x8*)&vt[(size_t)(16 + l16) * 64 + c * 32 + quad * 8];
      o0 = __builtin_amdgcn_mfma_f32_16x16x32_bf16(pf, vf0, o0, 0, 0, 0);
      o1 = __builtin_amdgcn_mfma_f32_16x16x32_bf16(pf, vf1, o1, 0, 0, 0);
    }
  }
#pragma unroll
  for (int r = 0; r < 4; r++) {
    Om[wave][quad * 4 + r][l16] = o0[r];
    Om[wave][quad * 4 + r][16 + l16] = o1[r];
  }
  if (l16 == 0) {
#pragma unroll
    for (int r = 0; r < 4; r++) {
      Ml[wave][quad * 4 + r][0] = mrun[r];
      Ml[wave][quad * 4 + r][1] = lrun[r];
    }
  }
  __syncthreads();
  {
    const int q = tid >> 3;
    const int c4 = (tid & 7) * 4;
    const float m0 = Ml[0][q][0], m1 = Ml[1][q][0];
    const float M = fmaxf(m0, m1);
    const float a0 = __expf(m0 - M), a1 = __expf(m1 - M);
    const float lsum = a0 * Ml[0][q][1] + a1 * Ml[1][q][1];
    const int qg = qt * 16 + q;
    if (qg < NQc) {
      const float inv = 1.f / lsum;
      float4 o;
      o.x = (a0 * Om[0][q][c4 + 0] + a1 * Om[1][q][c4 + 0]) * inv;
      o.y = (a0 * Om[0][q][c4 + 1] + a1 * Om[1][q][c4 + 1]) * inv;
      o.z = (a0 * Om[0][q][c4 + 2] + a1 * Om[1][q][c4 + 2]) * inv;
      o.w = (a0 * Om[0][q][c4 + 3] + a1 * Om[1][q][c4 + 3]) * inv;
      const int b = bh >> 3, h = bh & 7;
      *(float4*)&sa[(size_t)(b * NQc + qg) * 256 + h * 32 + c4] = o;
    }
  }
}

// ---------------------------------------------------------------------------
__global__ __launch_bounds__(256) void sample_k(
    const float* __restrict__ awlin, const float* __restrict__ off,
    const float* __restrict__ refp, const short* __restrict__ value,
    float* __restrict__ accout) {
  const int wid = blockIdx.x * 4 + (threadIdx.x >> 6);
  const int lane = threadIdx.x & 63;
  const int bq = wid >> 3, h = wid & 7;
  const int b = bq / NQc;
  const int l16 = lane & 15;

  float wraw = awlin[(size_t)bq * 128 + h * 16 + l16];
  float mx = wraw;
#pragma unroll
  for (int d = 1; d < 16; d <<= 1) mx = fmaxf(mx, __shfl_xor(mx, d));
  float e = __expf(wraw - mx), ssum = e;
#pragma unroll
  for (int d = 1; d < 16; d <<= 1) ssum += __shfl_xor(ssum, d);
  const float wnorm = e / ssum;

  const int ch = lane & 31, sub = lane >> 5;
  float facc = 0.f;
#pragma unroll
  for (int it = 0; it < 8; it++) {
    const int pt = it * 2 + sub;
    const float w = __shfl(wnorm, pt);
    const int l = pt >> 2;
    const int W = 128 >> l;
    const int start = (l == 0) ? 0 : (l == 1) ? 16384 : (l == 2) ? 20480 : 21504;
    const float offx = off[(size_t)bq * 256 + h * 32 + pt * 2];
    const float offy = off[(size_t)bq * 256 + h * 32 + pt * 2 + 1];
    const float rx = refp[(size_t)bq * 8 + l * 2];
    const float ry = refp[(size_t)bq * 8 + l * 2 + 1];
    const float x = rx * (float)W + offx - 0.5f;
    const float y = ry * (float)W + offy - 0.5f;
    const float x0f = floorf(x), y0f = floorf(y);
    const float wx = x - x0f, wy = y - y0f;
    const int x0 = (int)x0f, y0 = (int)y0f;
    const short* vbp = value + ((size_t)b * Sc + start) * 256 + h * 32 + ch;
#pragma unroll
    for (int c4 = 0; c4 < 4; c4++) {
      const int dx = c4 & 1, dy = c4 >> 1;
      const int xi = x0 + dx, yi = y0 + dy;
      const bool valid = (xi >= 0) && (xi < W) && (yi >= 0) && (yi < W);
      const int xc = min(max(xi, 0), W - 1);
      const int yc = min(max(yi, 0), W - 1);
      const float gvv = bf2f(vbp[(size_t)(yc * W + xc) * 256]);
      const float ww = (dx ? wx : 1.f - wx) * (dy ? wy : 1.f - wy);
      facc += valid ? w * ww * gvv : 0.f;
    }
  }
  facc += __shfl_xor(facc, 32);
  if (lane < 32) accout[(size_t)bq * 256 + h * 32 + ch] = facc;
}

// ---------------------------------------------------------------------------
extern "C" void kernel_launch(void* const* d_in, const int* in_sizes, int n_in,
                              void* d_out, int out_size, void* d_ws,
                              size_t ws_size, hipStream_t stream) {
  const float* tgt = (const float*)d_in[0];
  const float* query_pos = (const float*)d_in[1];
  const float* refp = (const float*)d_in[2];
  const float* memory = (const float*)d_in[3];
  const float* in_proj_w = (const float*)d_in[4];
  const float* in_proj_b = (const float*)d_in[5];
  const float* out_proj_w = (const float*)d_in[6];
  const float* out_proj_b = (const float*)d_in[7];
  const float* ln1_g = (const float*)d_in[8];
  const float* ln1_b = (const float*)d_in[9];
  const float* ln2_g = (const float*)d_in[10];
  const float* ln2_b = (const float*)d_in[11];
  const float* ln3_g = (const float*)d_in[12];
  const float* ln3_b = (const float*)d_in[13];
  const float* vproj_w = (const float*)d_in[14];
  const float* vproj_b = (const float*)d_in[15];
  const float* off_w = (const float*)d_in[16];
  const float* off_b = (const float*)d_in[17];
  const float* aw_w = (const float*)d_in[18];
  const float* aw_b = (const float*)d_in[19];
  const float* oproj_w = (const float*)d_in[20];
  const float* oproj_b = (const float*)d_in[21];
  const float* lin1_w = (const float*)d_in[22];
  const float* lin1_b = (const float*)d_in[23];
  const float* lin2_w = (const float*)d_in[24];
  const float* lin2_b = (const float*)d_in[25];
  const unsigned char* mem_mask = (const unsigned char*)d_in[27];
  float* out = (float*)d_out;

  float* ws = (float*)d_ws;
  short* qbf = (short*)(ws + 921600);  // qbf|kbf|vtbf: 3*983040 shorts
  float* sa = ws + 3686400;
  float* tgt2 = ws + 5529600;
  float* query = ws + 6451200;
  float* offb = ws + 7372800;
  float* awlin = ws + 8294400;
  float* accb = ws + 8755200;
  float* tgt3 = ws + 9676800;
  float* ff1 = ws + 10598400;     // [3600][1024]
  short* valueBf = (short*)(ws + 14284800);  // 22282240 shorts
  short* wbase = valueBf + 22282240;
  short* inT = wbase + 0;         // [8][768][32]
  short* outT = wbase + 196608;
  short* vT = wbase + 262144;
  short* oT = wbase + 327680;
  short* lin1T = wbase + 393216;  // [8][1024][32]
  short* lin2T = wbase + 655360;  // [32][256][32]

  pack_all_k<<<896, 256, 0, stream>>>(in_proj_w, inT, out_proj_w, outT,
                                      vproj_w, vT, oproj_w, oT,
                                      lin1_w, lin1T, lin2_w, lin2T);

  // fused q|k|v projection -> bf16 MFMA-layout buffers
  gemmv_k<4, 0, 32><<<113 * 3, 256, 0, stream>>>(
      tgt, query_pos, inT, in_proj_b, qbf, nullptr, M1, 768, 256,
      nullptr, nullptr, nullptr, nullptr, nullptr, nullptr);
  attn_k<<<Bc * Hc * QT16, 128, 0, stream>>>(qbf, qbf + QKo, qbf + 2 * QKo, sa);
  // out_proj + residual + LN2, and query = tgt2 + query_pos
  gemmv_k<3, 0, 32><<<113, 256, 0, stream>>>(
      sa, nullptr, outT, out_proj_b, tgt2, nullptr, M1, 256, 256,
      nullptr, ln2_g, ln2_b, tgt, query_pos, query);
  // value = memory @ vproj -> bf16 (full-N 32-row tiles, 6 blocks/CU v8)
  gemm_val_k<<<2720, 256, 0, stream>>>(memory, vT, vproj_b, valueBf, Bc * Sc, mem_mask);
  // off + aw (exact fp32: sampler-amplified path)
  gemm32_offaw_k<<<342, 256, 0, stream>>>(query, off_w, off_b, offb, aw_w, aw_b, awlin);
  sample_k<<<Bc * NQc * Hc / 4, 256, 0, stream>>>(awlin, offb, refp, valueBf, accb);
  // oproj + residual + LN1
  gemmv_k<3, 0, 32><<<113, 256, 0, stream>>>(
      accb, nullptr, oT, oproj_b, tgt3, nullptr, M1, 256, 256,
      nullptr, ln1_g, ln1_b, tgt2, nullptr, nullptr);
  // FFN
  gemmv_k<0, 1, 64><<<57 * 4, 256, 0, stream>>>(
      tgt3, nullptr, lin1T, lin1_b, ff1, nullptr, M1, 1024, 256,
      nullptr, nullptr, nullptr, nullptr, nullptr, nullptr);
  gemmv_k<3, 0, 32><<<113, 256, 0, stream>>>(
      ff1, nullptr, lin2T, lin2_b, out, nullptr, M1, 256, 1024,
      nullptr, ln3_g, ln3_b, tgt3, nullptr, nullptr);
}

// Round 9
// 396.166 us; speedup vs baseline: 3.8697x; 1.0474x over previous
//
#include <hip/hip_runtime.h>
#include <hip/hip_bf16.h>

typedef __attribute__((ext_vector_type(8))) short bf16x8;
typedef __attribute__((ext_vector_type(4))) short bf16x4;
typedef __attribute__((ext_vector_type(4))) float f32x4;

#define DEV static __device__ __forceinline__

constexpr int Bc = 4, NQc = 900, Hc = 8, Sc = 21760;
constexpr int M1 = Bc * NQc;           // 3600
constexpr int NQT = (NQc + 63) / 64;   // 15 key tiles of 64
constexpr int QT16 = (NQc + 15) / 16;  // 57 query tiles of 16
constexpr int QKo = Bc * Hc * 960 * 32;  // 983040: size of one [b][h][960][32] buf

DEV short f2bf(float f) {
  union { __hip_bfloat16 h; short s; } u;
  u.h = __float2bfloat16(f);
  return u.s;
}
DEV float bf2f(short s) {
  union { short s; __hip_bfloat16 h; } u;
  u.s = s;
  return __bfloat162float(u.h);
}

// ---------------------------------------------------------------------------
// Pack W[K][N] f32 -> k-tiled bf16 [K/32][N][32]
DEV void pack_body(const float* W, short* Wt, int K, int N, int t) {
  int n = t % N;
  int k4 = (t / N) * 4;
  bf16x4 o;
  o[0] = f2bf(W[(size_t)(k4 + 0) * N + n]);
  o[1] = f2bf(W[(size_t)(k4 + 1) * N + n]);
  o[2] = f2bf(W[(size_t)(k4 + 2) * N + n]);
  o[3] = f2bf(W[(size_t)(k4 + 3) * N + n]);
  *(bf16x4*)&Wt[((size_t)(k4 >> 5) * N + n) * 32 + (k4 & 31)] = o;
}

__global__ __launch_bounds__(256) void pack_all_k(
    const float* w0, short* t0, const float* w1, short* t1,
    const float* w2, short* t2, const float* w3, short* t3,
    const float* w4, short* t4, const float* w5, short* t5) {
  int t = blockIdx.x * 256 + threadIdx.x;
  if (t < 49152) pack_body(w0, t0, 256, 768, t);
  else if (t < 65536) pack_body(w1, t1, 256, 256, t - 49152);
  else if (t < 81920) pack_body(w2, t2, 256, 256, t - 65536);
  else if (t < 98304) pack_body(w3, t3, 256, 256, t - 81920);
  else if (t < 163840) pack_body(w4, t4, 256, 1024, t - 98304);
  else pack_body(w5, t5, 1024, 256, t - 163840);
}

// ---------------------------------------------------------------------------
// Unified MT x 256N bf16 MFMA GEMM, K-step 32, distance-2 register prefetch.
// MODE 0: f32 out (+ACT relu)
// MODE 3: LN epilogue (N=256): Cv = LN(resid + A@W + b)*g + beta [+ out2=+qpos]
// MODE 4: qkv: bn0 -> qbf (scaled bf16 [bh][960][32]), bn1 -> kbf (same),
//         bn2 -> vtbf (bf16 [bh][15][32ch][64key]); q,k add A2.
template <int MODE, int ACT, int MT>
__global__ __launch_bounds__(256) void gemmv_k(
    const float* __restrict__ A, const float* __restrict__ A2,
    const short* __restrict__ Wt, const float* __restrict__ bias,
    void* __restrict__ Cv, float* __restrict__ C2, int M, int N, int K,
    const unsigned char* __restrict__ rowmask, const float* __restrict__ g,
    const float* __restrict__ beta, const float* __restrict__ resid,
    const float* __restrict__ qpos, float* __restrict__ out2) {
  constexpr int IT = MT / 16;
  __shared__ short As[MT * 40];
  __shared__ short Ws[256 * 40];
  const int nb = N >> 8;
  const int mb = blockIdx.x / nb, bn = blockIdx.x - mb * nb;
  const int tid = threadIdx.x;
  const int lane = tid & 63, wave = tid >> 6;
  const int l16 = lane & 15, quad = lane >> 4;
  const int sr = (MT == 64) ? (tid >> 2) : (tid >> 3);
  const int sk = (MT == 64) ? ((tid & 3) * 8) : ((tid & 7) * 4);
  const int arow = mb * MT + sr;
  const bool aval = arow < M;
  const bool useA2 = (MODE == 4) ? (bn < 2) : (A2 != nullptr);
  const float* ap = A + (size_t)arow * K + sk;
  const float* ap2 = (A2 ? A2 : A) + (size_t)arow * K + sk;
  const short* wp = Wt + (size_t)(bn * 256 + tid) * 32;
  const size_t wstep = (size_t)N * 32;
  const int KT = K >> 5;

  f32x4 acc[IT][4] = {};
  float4 pa0[2] = {}, pa1[2] = {};
  bf16x8 pw[2][4];

  auto loadA = [&](int s, int it) {
    if (aval) {
      const float* p = ap + it * 32;
      pa0[s] = *(const float4*)p;
      if constexpr (MT == 64) pa1[s] = *(const float4*)(p + 4);
      if (useA2) {
        const float* p2 = ap2 + it * 32;
        float4 q0 = *(const float4*)p2;
        pa0[s].x += q0.x; pa0[s].y += q0.y; pa0[s].z += q0.z; pa0[s].w += q0.w;
        if constexpr (MT == 64) {
          float4 q1 = *(const float4*)(p2 + 4);
          pa1[s].x += q1.x; pa1[s].y += q1.y; pa1[s].z += q1.z; pa1[s].w += q1.w;
        }
      }
    }
  };
  auto loadW = [&](int s, int it) {
    const short* p = wp + (size_t)it * wstep;
    pw[s][0] = *(const bf16x8*)(p + 0);
    pw[s][1] = *(const bf16x8*)(p + 8);
    pw[s][2] = *(const bf16x8*)(p + 16);
    pw[s][3] = *(const bf16x8*)(p + 24);
  };
  auto stage = [&](int s) {
    if constexpr (MT == 64) {
      bf16x8 t;
      t[0] = f2bf(pa0[s].x); t[1] = f2bf(pa0[s].y); t[2] = f2bf(pa0[s].z); t[3] = f2bf(pa0[s].w);
      t[4] = f2bf(pa1[s].x); t[5] = f2bf(pa1[s].y); t[6] = f2bf(pa1[s].z); t[7] = f2bf(pa1[s].w);
      *(bf16x8*)&As[sr * 40 + sk] = t;
    } else {
      bf16x4 t;
      t[0] = f2bf(pa0[s].x); t[1] = f2bf(pa0[s].y); t[2] = f2bf(pa0[s].z); t[3] = f2bf(pa0[s].w);
      *(bf16x4*)&As[sr * 40 + sk] = t;
    }
    short* wd = &Ws[tid * 40];
    *(bf16x8*)(wd + 0) = pw[s][0];
    *(bf16x8*)(wd + 8) = pw[s][1];
    *(bf16x8*)(wd + 16) = pw[s][2];
    *(bf16x8*)(wd + 24) = pw[s][3];
  };
  auto compute = [&]() {
    bf16x8 af[IT], bfr[4];
#pragma unroll
    for (int i = 0; i < IT; i++)
      af[i] = *(const bf16x8*)&As[(i * 16 + l16) * 40 + quad * 8];
#pragma unroll
    for (int j = 0; j < 4; j++)
      bfr[j] = *(const bf16x8*)&Ws[(wave * 64 + j * 16 + l16) * 40 + quad * 8];
#pragma unroll
    for (int i = 0; i < IT; i++)
#pragma unroll
      for (int j = 0; j < 4; j++)
        acc[i][j] = __builtin_amdgcn_mfma_f32_16x16x32_bf16(af[i], bfr[j], acc[i][j], 0, 0, 0);
  };

  loadA(0, 0); loadW(0, 0);
  loadA(1, 1); loadW(1, 1);
  for (int it = 0; it < KT; it += 2) {
    stage(0);
    __syncthreads();
    if (it + 2 < KT) { loadA(0, it + 2); loadW(0, it + 2); }
    compute();
    __syncthreads();
    stage(1);
    __syncthreads();
    if (it + 3 < KT) { loadA(1, it + 3); loadW(1, it + 3); }
    compute();
    __syncthreads();
  }

  // ---- epilogues ----
  if constexpr (MODE == 4) {
    short* base = (short*)Cv;
#pragma unroll
    for (int i = 0; i < IT; i++)
#pragma unroll
      for (int r = 0; r < 4; r++) {
        const int m = mb * MT + i * 16 + quad * 4 + r;
        if (m >= M) continue;
        const int b = m / NQc, q = m - b * NQc;
#pragma unroll
        for (int j = 0; j < 4; j++) {
          const int cl = wave * 64 + j * 16 + l16;
          const float v = acc[i][j][r] + bias[bn * 256 + cl];
          const int h = cl >> 5, ch = cl & 31;
          if (bn == 0) {
            base[((size_t)(b * 8 + h) * 960 + q) * 32 + ch] =
                f2bf(v * 0.17677669529663687f);
          } else if (bn == 1) {
            base[QKo + ((size_t)(b * 8 + h) * 960 + q) * 32 + ch] = f2bf(v);
          } else {
            base[2 * QKo + ((((size_t)(b * 8 + h) * 15 + (q >> 6)) * 32 + ch) * 64 + (q & 63))] = f2bf(v);
          }
        }
      }
  } else if constexpr (MODE == 0) {
#pragma unroll
    for (int i = 0; i < IT; i++)
#pragma unroll
      for (int j = 0; j < 4; j++) {
        const int cl = wave * 64 + j * 16 + l16;
        const int col = bn * 256 + cl;
        const float bb = bias[col];
#pragma unroll
        for (int r = 0; r < 4; r++) {
          const int m = mb * MT + i * 16 + quad * 4 + r;
          if (m < M) {
            float v = acc[i][j][r] + bb;
            if (ACT == 1) v = fmaxf(v, 0.f);
            ((float*)Cv)[(size_t)m * N + col] = v;
          }
        }
      }
  } else {  // MODE 3: fused LayerNorm epilogue (N==256)
#pragma unroll
    for (int j = 0; j < 4; j++) {
      const int cl = wave * 64 + j * 16 + l16;
      const float bb = bias[cl];
#pragma unroll
      for (int i = 0; i < IT; i++)
#pragma unroll
        for (int r = 0; r < 4; r++) {
          const int m = mb * MT + i * 16 + quad * 4 + r;
          const float rs = (m < M) ? resid[(size_t)m * 256 + cl] : 0.f;
          acc[i][j][r] += bb + rs;
        }
    }
    float2* pr = (float2*)As;
#pragma unroll
    for (int i = 0; i < IT; i++)
#pragma unroll
      for (int r = 0; r < 4; r++) {
        float s = 0.f, q = 0.f;
#pragma unroll
        for (int j = 0; j < 4; j++) {
          s += acc[i][j][r];
          q += acc[i][j][r] * acc[i][j][r];
        }
#pragma unroll
        for (int d = 1; d < 16; d <<= 1) {
          s += __shfl_xor(s, d);
          q += __shfl_xor(q, d);
        }
        if (l16 == 0) pr[(i * 16 + quad * 4 + r) * 4 + wave] = make_float2(s, q);
      }
    __syncthreads();
#pragma unroll
    for (int i = 0; i < IT; i++)
#pragma unroll
      for (int r = 0; r < 4; r++) {
        const int ml = i * 16 + quad * 4 + r;
        float2 p0 = pr[ml * 4 + 0], p1 = pr[ml * 4 + 1];
        float2 p2 = pr[ml * 4 + 2], p3 = pr[ml * 4 + 3];
        const float sum = p0.x + p1.x + p2.x + p3.x;
        const float sq = p0.y + p1.y + p2.y + p3.y;
        const float mean = sum * (1.f / 256.f);
        const float var = sq * (1.f / 256.f) - mean * mean;
        const float rstd = rsqrtf(var + 1e-5f);
        const int m = mb * MT + ml;
        if (m < M) {
#pragma unroll
          for (int j = 0; j < 4; j++) {
            const int cl = wave * 64 + j * 16 + l16;
            const float o = (acc[i][j][r] - mean) * rstd * g[cl] + beta[cl];
            ((float*)Cv)[(size_t)m * 256 + cl] = o;
            if (out2) out2[(size_t)m * 256 + cl] = o + qpos[(size_t)m * 256 + cl];
          }
        }
      }
  }
}

// ---------------------------------------------------------------------------
// Value projection GEMM, v6 (round-6 verified best: 52.4 us): full-N blocks,
// A and B read once at every cache level. A via global_load_lds with
// pre-swizzled source + XOR read; B direct global->reg distance-1 dbuf.
// One block per 64-row tile (grid 1360 = M/64 exact).
__global__ __launch_bounds__(256, 3) void gemm_val_k(
    const float* __restrict__ A, const short* __restrict__ Wt,
    const float* __restrict__ bias, short* __restrict__ Cv, int M,
    const unsigned char* __restrict__ rowmask) {
  __shared__ float As[2][64 * 32];  // 16 KB
  const int mb = blockIdx.x;
  const int tid = threadIdx.x;
  const int lane = tid & 63, wave = tid >> 6;
  const int l16 = lane & 15, quad = lane >> 4;

  // B fragment: col = wave*64 + j*16 + l16, k-tile it, sub-k quad*8
  const short* wp = Wt + (size_t)(wave * 64 + l16) * 32 + quad * 8;

  // A staging source (pre-swizzled chunk so linear DMA + XOR read = identity)
  const int srow = lane >> 3;
  const int schunk = ((lane & 7) ^ srow) * 4;  // swizzled k-chunk (floats)
  const float* abase = A + (size_t)(mb * 64 + wave * 8 + srow) * 256 + schunk;

  f32x4 acc[4][4] = {};
  bf16x8 pb[2][4];

  auto stage = [&](int buf, int it) {
#pragma unroll
    for (int call = 0; call < 2; ++call) {
      const float* src = abase + (size_t)call * (32 * 256) + it * 32;
      float* dst = &As[buf][(call * 32 + wave * 8) * 32];
      __builtin_amdgcn_global_load_lds(
          (const __attribute__((address_space(1))) void*)src,
          (__attribute__((address_space(3))) void*)dst, 16, 0, 0);
    }
  };
  auto loadB = [&](int s, int it) {
#pragma unroll
    for (int j = 0; j < 4; j++)
      pb[s][j] = *(const bf16x8*)(wp + (size_t)(it * 256 + j * 16) * 32);
  };
  auto compute = [&](int cur) {
    bf16x8 af[4];
#pragma unroll
    for (int i = 0; i < 4; i++) {
      const int row = i * 16 + l16;
      const int cb = row & 7;
      const float4 a0 =
          *(const float4*)&As[cur][row * 32 + (((quad * 2) ^ cb) << 2)];
      const float4 a1 =
          *(const float4*)&As[cur][row * 32 + (((quad * 2 + 1) ^ cb) << 2)];
      af[i][0] = f2bf(a0.x); af[i][1] = f2bf(a0.y);
      af[i][2] = f2bf(a0.z); af[i][3] = f2bf(a0.w);
      af[i][4] = f2bf(a1.x); af[i][5] = f2bf(a1.y);
      af[i][6] = f2bf(a1.z); af[i][7] = f2bf(a1.w);
    }
#pragma unroll
    for (int i = 0; i < 4; i++)
#pragma unroll
      for (int j = 0; j < 4; j++)
        acc[i][j] = __builtin_amdgcn_mfma_f32_16x16x32_bf16(af[i], pb[cur][j],
                                                            acc[i][j], 0, 0, 0);
  };

  stage(0, 0);
  loadB(0, 0);
  __syncthreads();  // As[0] + pb[0] ready
  for (int it = 0; it < 8; ++it) {
    const int cur = it & 1;
    if (it + 1 < 8) { stage(cur ^ 1, it + 1); loadB(cur ^ 1, it + 1); }
    compute(cur);     // ds_read + MFMA while next-tile loads fly
    __syncthreads();  // drains stage/loadB(it+1); all waves done with As[cur]
  }

  float bb[4];
#pragma unroll
  for (int j = 0; j < 4; j++) bb[j] = bias[wave * 64 + j * 16 + l16];
#pragma unroll
  for (int i = 0; i < 4; i++)
#pragma unroll
    for (int r = 0; r < 4; r++) {
      const int m = mb * 64 + i * 16 + quad * 4 + r;
      const bool mk = rowmask[m] != 0;
#pragma unroll
      for (int j = 0; j < 4; j++) {
        const int cl = wave * 64 + j * 16 + l16;
        float v = acc[i][j][r] + bb[j];
        if (mk) v = 0.f;
        Cv[(size_t)m * 256 + cl] = f2bf(v);
      }
    }
}

// ---------------------------------------------------------------------------
// Exact fp32 GEMM body (off/aw: sampler-amplified precision path).
// Round-9: distance-1 register prefetch — the K-loop previously exposed the
// full global-load latency between both barriers every one of its 16
// iterations (load -> sync -> compute -> sync). Now the k0+16 loads are
// issued right after the first barrier and fly under the 16-step FMA unroll.
DEV void gemm32_body(const float* __restrict__ A, const float* __restrict__ W,
                     const float* __restrict__ bias, float* __restrict__ C,
                     int M, int N, int K, int bid) {
  __shared__ float Asf[16][64];
  __shared__ float Bsf[16][68];
  const int nb = N >> 6;
  const int bm = bid / nb, bn = bid % nb;
  const int tid = threadIdx.x;
  const int tm = tid >> 4, tn = tid & 15;
  const int am = tid >> 2, akk = (tid & 3) * 4;   // A stage coords
  const int bkk = tid >> 4, bn4 = (tid & 15) * 4; // B stage coords
  const int arow = bm * 64 + am;
  float acc[4][4] = {};

  float4 pa, pb;
  auto loadA = [&](int k0) {
    pa = (arow < M) ? *(const float4*)(A + (size_t)arow * K + k0 + akk)
                    : make_float4(0.f, 0.f, 0.f, 0.f);
  };
  auto loadB = [&](int k0) {
    pb = *(const float4*)(W + (size_t)(k0 + bkk) * N + bn * 64 + bn4);
  };

  loadA(0); loadB(0);
  for (int k0 = 0; k0 < K; k0 += 16) {
    Asf[akk + 0][am] = pa.x; Asf[akk + 1][am] = pa.y;
    Asf[akk + 2][am] = pa.z; Asf[akk + 3][am] = pa.w;
    *(float4*)&Bsf[bkk][bn4] = pb;
    __syncthreads();
    if (k0 + 16 < K) { loadA(k0 + 16); loadB(k0 + 16); }  // prefetch in flight
#pragma unroll
    for (int kk = 0; kk < 16; kk++) {
      float a[4], b[4];
#pragma unroll
      for (int i = 0; i < 4; i++) a[i] = Asf[kk][tm * 4 + i];
#pragma unroll
      for (int j = 0; j < 4; j++) b[j] = Bsf[kk][tn * 4 + j];
#pragma unroll
      for (int i = 0; i < 4; i++)
#pragma unroll
        for (int j = 0; j < 4; j++) acc[i][j] = fmaf(a[i], b[j], acc[i][j]);
    }
    __syncthreads();
  }
#pragma unroll
  for (int i = 0; i < 4; i++) {
    const int row = bm * 64 + tm * 4 + i;
    if (row >= M) continue;
#pragma unroll
    for (int j = 0; j < 4; j++) {
      const int col = bn * 64 + tn * 4 + j;
      C[(size_t)row * N + col] = acc[i][j] + bias[col];
    }
  }
}

__global__ __launch_bounds__(256) void gemm32_offaw_k(
    const float* __restrict__ query, const float* __restrict__ off_w,
    const float* __restrict__ off_b, float* __restrict__ offb,
    const float* __restrict__ aw_w, const float* __restrict__ aw_b,
    float* __restrict__ awlin) {
  if (blockIdx.x < 228)
    gemm32_body(query, off_w, off_b, offb, M1, 256, 256, blockIdx.x);
  else
    gemm32_body(query, aw_w, aw_b, awlin, M1, 128, 256, blockIdx.x - 228);
}

// ---------------------------------------------------------------------------
// Flash attention from pre-packed bf16 buffers. Block = (b,h,16 queries),
// 2 waves split key tiles even/odd. Hot loop: coalesced bf16x8 global loads
// (Q,K from [bh][960][32], V^T from [bh][15][32][64]) straight into MFMA —
// no f2bf, no V staging, no barriers. Single merge barrier at end.
__global__ __launch_bounds__(128) void attn_k(const short* __restrict__ qbf,
                                              const short* __restrict__ kbf,
                                              const short* __restrict__ vtbf,
                                              float* __restrict__ sa) {
  __shared__ short Pb[2][16 * 72];
  __shared__ float Om[2][16][32];
  __shared__ float Ml[2][16][2];
  const int bid = blockIdx.x;
  const int qt = bid % QT16, bh = bid / QT16;
  const int tid = threadIdx.x, lane = tid & 63, wave = tid >> 6;
  const int l16 = lane & 15, quad = lane >> 4;

  const int q_local = min(qt * 16 + l16, NQc - 1);
  const bf16x8 qf = *(const bf16x8*)&qbf[((size_t)bh * 960 + q_local) * 32 + quad * 8];
  const short* kb = kbf + (size_t)bh * 960 * 32;
  const short* vb = vtbf + (size_t)bh * 15 * 32 * 64;

  f32x4 o0 = {}, o1 = {};
  float mrun[4] = {-1e30f, -1e30f, -1e30f, -1e30f};
  float lrun[4] = {0.f, 0.f, 0.f, 0.f};
  short* pw = Pb[wave];

  for (int kt = wave; kt < NQT; kt += 2) {
    const int k0 = kt * 64;
    f32x4 s[4];
#pragma unroll
    for (int st = 0; st < 4; st++) {
      const int key = k0 + st * 16 + l16;
      const bf16x8 kf = *(const bf16x8*)&kb[(size_t)key * 32 + quad * 8];
      f32x4 z = {};
      s[st] = __builtin_amdgcn_mfma_f32_16x16x32_bf16(qf, kf, z, 0, 0, 0);
      if (key >= NQc) { s[st][0] = -1e30f; s[st][1] = -1e30f; s[st][2] = -1e30f; s[st][3] = -1e30f; }
    }
    float mnew[4], alpha[4];
#pragma unroll
    for (int r = 0; r < 4; r++) {
      float mx = fmaxf(fmaxf(s[0][r], s[1][r]), fmaxf(s[2][r], s[3][r]));
#pragma unroll
      for (int d = 1; d < 16; d <<= 1) mx = fmaxf(mx, __shfl_xor(mx, d));
      mnew[r] = fmaxf(mrun[r], mx);
      alpha[r] = __expf(mrun[r] - mnew[r]);
      mrun[r] = mnew[r];
    }
    float tsum[4] = {0.f, 0.f, 0.f, 0.f};
#pragma unroll
    for (int st = 0; st < 4; st++)
#pragma unroll
      for (int r = 0; r < 4; r++) {
        float p = __expf(s[st][r] - mnew[r]);
        s[st][r] = p;
        tsum[r] += p;
      }
#pragma unroll
    for (int r = 0; r < 4; r++) {
      float t = tsum[r];
#pragma unroll
      for (int d = 1; d < 16; d <<= 1) t += __shfl_xor(t, d);
      lrun[r] = lrun[r] * alpha[r] + t;
      o0[r] *= alpha[r];
      o1[r] *= alpha[r];
    }
    // P: C-layout -> A-layout via per-wave LDS (wave-local, no barrier)
#pragma unroll
    for (int st = 0; st < 4; st++)
#pragma unroll
      for (int r = 0; r < 4; r++)
        pw[(quad * 4 + r) * 72 + st * 16 + l16] = f2bf(s[st][r]);
    const short* vt = vb + kt * (32 * 64);
#pragma unroll
    for (int c = 0; c < 2; c++) {
      bf16x8 pf = *(const bf16x8*)&pw[l16 * 72 + c * 32 + quad * 8];
      bf16x8 vf0 = *(const bf16x8*)&vt[(size_t)l16 * 64 + c * 32 + quad * 8];
      bf16x8 vf1 = *(const bf16x8*)&vt[(size_t)(16 + l16) * 64 + c * 32 + quad * 8];
      o0 = __builtin_amdgcn_mfma_f32_16x16x32_bf16(pf, vf0, o0, 0, 0, 0);
      o1 = __builtin_amdgcn_mfma_f32_16x16x32_bf16(pf, vf1, o1, 0, 0, 0);
    }
  }
#pragma unroll
  for (int r = 0; r < 4; r++) {
    Om[wave][quad * 4 + r][l16] = o0[r];
    Om[wave][quad * 4 + r][16 + l16] = o1[r];
  }
  if (l16 == 0) {
#pragma unroll
    for (int r = 0; r < 4; r++) {
      Ml[wave][quad * 4 + r][0] = mrun[r];
      Ml[wave][quad * 4 + r][1] = lrun[r];
    }
  }
  __syncthreads();
  {
    const int q = tid >> 3;
    const int c4 = (tid & 7) * 4;
    const float m0 = Ml[0][q][0], m1 = Ml[1][q][0];
    const float M = fmaxf(m0, m1);
    const float a0 = __expf(m0 - M), a1 = __expf(m1 - M);
    const float lsum = a0 * Ml[0][q][1] + a1 * Ml[1][q][1];
    const int qg = qt * 16 + q;
    if (qg < NQc) {
      const float inv = 1.f / lsum;
      float4 o;
      o.x = (a0 * Om[0][q][c4 + 0] + a1 * Om[1][q][c4 + 0]) * inv;
      o.y = (a0 * Om[0][q][c4 + 1] + a1 * Om[1][q][c4 + 1]) * inv;
      o.z = (a0 * Om[0][q][c4 + 2] + a1 * Om[1][q][c4 + 2]) * inv;
      o.w = (a0 * Om[0][q][c4 + 3] + a1 * Om[1][q][c4 + 3]) * inv;
      const int b = bh >> 3, h = bh & 7;
      *(float4*)&sa[(size_t)(b * NQc + qg) * 256 + h * 32 + c4] = o;
    }
  }
}

// ---------------------------------------------------------------------------
__global__ __launch_bounds__(256) void sample_k(
    const float* __restrict__ awlin, const float* __restrict__ off,
    const float* __restrict__ refp, const short* __restrict__ value,
    float* __restrict__ accout) {
  const int wid = blockIdx.x * 4 + (threadIdx.x >> 6);
  const int lane = threadIdx.x & 63;
  const int bq = wid >> 3, h = wid & 7;
  const int b = bq / NQc;
  const int l16 = lane & 15;

  float wraw = awlin[(size_t)bq * 128 + h * 16 + l16];
  float mx = wraw;
#pragma unroll
  for (int d = 1; d < 16; d <<= 1) mx = fmaxf(mx, __shfl_xor(mx, d));
  float e = __expf(wraw - mx), ssum = e;
#pragma unroll
  for (int d = 1; d < 16; d <<= 1) ssum += __shfl_xor(ssum, d);
  const float wnorm = e / ssum;

  const int ch = lane & 31, sub = lane >> 5;
  float facc = 0.f;
#pragma unroll
  for (int it = 0; it < 8; it++) {
    const int pt = it * 2 + sub;
    const float w = __shfl(wnorm, pt);
    const int l = pt >> 2;
    const int W = 128 >> l;
    const int start = (l == 0) ? 0 : (l == 1) ? 16384 : (l == 2) ? 20480 : 21504;
    const float offx = off[(size_t)bq * 256 + h * 32 + pt * 2];
    const float offy = off[(size_t)bq * 256 + h * 32 + pt * 2 + 1];
    const float rx = refp[(size_t)bq * 8 + l * 2];
    const float ry = refp[(size_t)bq * 8 + l * 2 + 1];
    const float x = rx * (float)W + offx - 0.5f;
    const float y = ry * (float)W + offy - 0.5f;
    const float x0f = floorf(x), y0f = floorf(y);
    const float wx = x - x0f, wy = y - y0f;
    const int x0 = (int)x0f, y0 = (int)y0f;
    const short* vbp = value + ((size_t)b * Sc + start) * 256 + h * 32 + ch;
#pragma unroll
    for (int c4 = 0; c4 < 4; c4++) {
      const int dx = c4 & 1, dy = c4 >> 1;
      const int xi = x0 + dx, yi = y0 + dy;
      const bool valid = (xi >= 0) && (xi < W) && (yi >= 0) && (yi < W);
      const int xc = min(max(xi, 0), W - 1);
      const int yc = min(max(yi, 0), W - 1);
      const float gvv = bf2f(vbp[(size_t)(yc * W + xc) * 256]);
      const float ww = (dx ? wx : 1.f - wx) * (dy ? wy : 1.f - wy);
      facc += valid ? w * ww * gvv : 0.f;
    }
  }
  facc += __shfl_xor(facc, 32);
  if (lane < 32) accout[(size_t)bq * 256 + h * 32 + ch] = facc;
}

// ---------------------------------------------------------------------------
extern "C" void kernel_launch(void* const* d_in, const int* in_sizes, int n_in,
                              void* d_out, int out_size, void* d_ws,
                              size_t ws_size, hipStream_t stream) {
  const float* tgt = (const float*)d_in[0];
  const float* query_pos = (const float*)d_in[1];
  const float* refp = (const float*)d_in[2];
  const float* memory = (const float*)d_in[3];
  const float* in_proj_w = (const float*)d_in[4];
  const float* in_proj_b = (const float*)d_in[5];
  const float* out_proj_w = (const float*)d_in[6];
  const float* out_proj_b = (const float*)d_in[7];
  const float* ln1_g = (const float*)d_in[8];
  const float* ln1_b = (const float*)d_in[9];
  const float* ln2_g = (const float*)d_in[10];
  const float* ln2_b = (const float*)d_in[11];
  const float* ln3_g = (const float*)d_in[12];
  const float* ln3_b = (const float*)d_in[13];
  const float* vproj_w = (const float*)d_in[14];
  const float* vproj_b = (const float*)d_in[15];
  const float* off_w = (const float*)d_in[16];
  const float* off_b = (const float*)d_in[17];
  const float* aw_w = (const float*)d_in[18];
  const float* aw_b = (const float*)d_in[19];
  const float* oproj_w = (const float*)d_in[20];
  const float* oproj_b = (const float*)d_in[21];
  const float* lin1_w = (const float*)d_in[22];
  const float* lin1_b = (const float*)d_in[23];
  const float* lin2_w = (const float*)d_in[24];
  const float* lin2_b = (const float*)d_in[25];
  const unsigned char* mem_mask = (const unsigned char*)d_in[27];
  float* out = (float*)d_out;

  float* ws = (float*)d_ws;
  short* qbf = (short*)(ws + 921600);  // qbf|kbf|vtbf: 3*983040 shorts
  float* sa = ws + 3686400;
  float* tgt2 = ws + 5529600;
  float* query = ws + 6451200;
  float* offb = ws + 7372800;
  float* awlin = ws + 8294400;
  float* accb = ws + 8755200;
  float* tgt3 = ws + 9676800;
  float* ff1 = ws + 10598400;     // [3600][1024]
  short* valueBf = (short*)(ws + 14284800);  // 22282240 shorts
  short* wbase = valueBf + 22282240;
  short* inT = wbase + 0;         // [8][768][32]
  short* outT = wbase + 196608;
  short* vT = wbase + 262144;
  short* oT = wbase + 327680;
  short* lin1T = wbase + 393216;  // [8][1024][32]
  short* lin2T = wbase + 655360;  // [32][256][32]

  pack_all_k<<<896, 256, 0, stream>>>(in_proj_w, inT, out_proj_w, outT,
                                      vproj_w, vT, oproj_w, oT,
                                      lin1_w, lin1T, lin2_w, lin2T);

  // fused q|k|v projection -> bf16 MFMA-layout buffers
  gemmv_k<4, 0, 32><<<113 * 3, 256, 0, stream>>>(
      tgt, query_pos, inT, in_proj_b, qbf, nullptr, M1, 768, 256,
      nullptr, nullptr, nullptr, nullptr, nullptr, nullptr);
  attn_k<<<Bc * Hc * QT16, 128, 0, stream>>>(qbf, qbf + QKo, qbf + 2 * QKo, sa);
  // out_proj + residual + LN2, and query = tgt2 + query_pos
  gemmv_k<3, 0, 32><<<113, 256, 0, stream>>>(
      sa, nullptr, outT, out_proj_b, tgt2, nullptr, M1, 256, 256,
      nullptr, ln2_g, ln2_b, tgt, query_pos, query);
  // value = memory @ vproj -> bf16 (full-N once-per-cache-level v6)
  gemm_val_k<<<1360, 256, 0, stream>>>(memory, vT, vproj_b, valueBf, Bc * Sc, mem_mask);
  // off + aw (exact fp32, distance-1 prefetch)
  gemm32_offaw_k<<<342, 256, 0, stream>>>(query, off_w, off_b, offb, aw_w, aw_b, awlin);
  sample_k<<<Bc * NQc * Hc / 4, 256, 0, stream>>>(awlin, offb, refp, valueBf, accb);
  // oproj + residual + LN1
  gemmv_k<3, 0, 32><<<113, 256, 0, stream>>>(
      accb, nullptr, oT, oproj_b, tgt3, nullptr, M1, 256, 256,
      nullptr, ln1_g, ln1_b, tgt2, nullptr, nullptr);
  // FFN
  gemmv_k<0, 1, 64><<<57 * 4, 256, 0, stream>>>(
      tgt3, nullptr, lin1T, lin1_b, ff1, nullptr, M1, 1024, 256,
      nullptr, nullptr, nullptr, nullptr, nullptr, nullptr);
  gemmv_k<3, 0, 32><<<113, 256, 0, stream>>>(
      ff1, nullptr, lin2T, lin2_b, out, nullptr, M1, 256, 1024,
      nullptr, ln3_g, ln3_b, tgt3, nullptr, nullptr);
}

// Round 10
// 392.962 us; speedup vs baseline: 3.9012x; 1.0082x over previous
//
#include <hip/hip_runtime.h>
#include <hip/hip_bf16.h>

typedef __attribute__((ext_vector_type(8))) short bf16x8;
typedef __attribute__((ext_vector_type(4))) short bf16x4;
typedef __attribute__((ext_vector_type(4))) float f32x4;

#define DEV static __device__ __forceinline__

constexpr int Bc = 4, NQc = 900, Hc = 8, Sc = 21760;
constexpr int M1 = Bc * NQc;           // 3600
constexpr int NQT = (NQc + 63) / 64;   // 15 key tiles of 64
constexpr int QT16 = (NQc + 15) / 16;  // 57 query tiles of 16
constexpr int QKo = Bc * Hc * 960 * 32;  // 983040: size of one [b][h][960][32] buf

DEV short f2bf(float f) {
  union { __hip_bfloat16 h; short s; } u;
  u.h = __float2bfloat16(f);
  return u.s;
}
DEV float bf2f(short s) {
  union { short s; __hip_bfloat16 h; } u;
  u.s = s;
  return __bfloat162float(u.h);
}

// ---------------------------------------------------------------------------
// Pack W[K][N] f32 -> k-tiled bf16 [K/32][N][32]
DEV void pack_body(const float* W, short* Wt, int K, int N, int t) {
  int n = t % N;
  int k4 = (t / N) * 4;
  bf16x4 o;
  o[0] = f2bf(W[(size_t)(k4 + 0) * N + n]);
  o[1] = f2bf(W[(size_t)(k4 + 1) * N + n]);
  o[2] = f2bf(W[(size_t)(k4 + 2) * N + n]);
  o[3] = f2bf(W[(size_t)(k4 + 3) * N + n]);
  *(bf16x4*)&Wt[((size_t)(k4 >> 5) * N + n) * 32 + (k4 & 31)] = o;
}

__global__ __launch_bounds__(256) void pack_all_k(
    const float* w0, short* t0, const float* w1, short* t1,
    const float* w2, short* t2, const float* w3, short* t3,
    const float* w4, short* t4, const float* w5, short* t5) {
  int t = blockIdx.x * 256 + threadIdx.x;
  if (t < 49152) pack_body(w0, t0, 256, 768, t);
  else if (t < 65536) pack_body(w1, t1, 256, 256, t - 49152);
  else if (t < 81920) pack_body(w2, t2, 256, 256, t - 65536);
  else if (t < 98304) pack_body(w3, t3, 256, 256, t - 81920);
  else if (t < 163840) pack_body(w4, t4, 256, 1024, t - 98304);
  else pack_body(w5, t5, 1024, 256, t - 163840);
}

// ---------------------------------------------------------------------------
// Unified MT x 256N bf16 MFMA GEMM, K-step 32, distance-2 register prefetch.
// Round-10: double-stage / single-join inner loop — both K-tiles of a pair
// are staged into DISJOINT LDS halves, then ONE barrier, prefetch both next
// tiles, compute both, ONE barrier. Halves the barrier count (16 -> 8 for
// K=256; 64 -> 32 for FFN2's K=1024). Mechanism: these launches run 113-339
// blocks on 256 CUs (solo block per CU, no cross-block TLP), so every
// __syncthreads' implicit vmcnt(0) drain is fully exposed; fewer joins =
// less exposed latency. Stage/compute bodies unchanged except LDS-half idx.
// MODE 0: f32 out (+ACT relu)
// MODE 3: LN epilogue (N=256): Cv = LN(resid + A@W + b)*g + beta [+ out2=+qpos]
// MODE 4: qkv: bn0 -> qbf (scaled bf16 [bh][960][32]), bn1 -> kbf (same),
//         bn2 -> vtbf (bf16 [bh][15][32ch][64key]); q,k add A2.
template <int MODE, int ACT, int MT>
__global__ __launch_bounds__(256) void gemmv_k(
    const float* __restrict__ A, const float* __restrict__ A2,
    const short* __restrict__ Wt, const float* __restrict__ bias,
    void* __restrict__ Cv, float* __restrict__ C2, int M, int N, int K,
    const unsigned char* __restrict__ rowmask, const float* __restrict__ g,
    const float* __restrict__ beta, const float* __restrict__ resid,
    const float* __restrict__ qpos, float* __restrict__ out2) {
  constexpr int IT = MT / 16;
  __shared__ short As[2][MT * 40];
  __shared__ short Ws[2][256 * 40];
  const int nb = N >> 8;
  const int mb = blockIdx.x / nb, bn = blockIdx.x - mb * nb;
  const int tid = threadIdx.x;
  const int lane = tid & 63, wave = tid >> 6;
  const int l16 = lane & 15, quad = lane >> 4;
  const int sr = (MT == 64) ? (tid >> 2) : (tid >> 3);
  const int sk = (MT == 64) ? ((tid & 3) * 8) : ((tid & 7) * 4);
  const int arow = mb * MT + sr;
  const bool aval = arow < M;
  const bool useA2 = (MODE == 4) ? (bn < 2) : (A2 != nullptr);
  const float* ap = A + (size_t)arow * K + sk;
  const float* ap2 = (A2 ? A2 : A) + (size_t)arow * K + sk;
  const short* wp = Wt + (size_t)(bn * 256 + tid) * 32;
  const size_t wstep = (size_t)N * 32;
  const int KT = K >> 5;

  f32x4 acc[IT][4] = {};
  float4 pa0[2] = {}, pa1[2] = {};
  bf16x8 pw[2][4];

  auto loadA = [&](int s, int it) {
    if (aval) {
      const float* p = ap + it * 32;
      pa0[s] = *(const float4*)p;
      if constexpr (MT == 64) pa1[s] = *(const float4*)(p + 4);
      if (useA2) {
        const float* p2 = ap2 + it * 32;
        float4 q0 = *(const float4*)p2;
        pa0[s].x += q0.x; pa0[s].y += q0.y; pa0[s].z += q0.z; pa0[s].w += q0.w;
        if constexpr (MT == 64) {
          float4 q1 = *(const float4*)(p2 + 4);
          pa1[s].x += q1.x; pa1[s].y += q1.y; pa1[s].z += q1.z; pa1[s].w += q1.w;
        }
      }
    }
  };
  auto loadW = [&](int s, int it) {
    const short* p = wp + (size_t)it * wstep;
    pw[s][0] = *(const bf16x8*)(p + 0);
    pw[s][1] = *(const bf16x8*)(p + 8);
    pw[s][2] = *(const bf16x8*)(p + 16);
    pw[s][3] = *(const bf16x8*)(p + 24);
  };
  auto stage = [&](int s) {
    if constexpr (MT == 64) {
      bf16x8 t;
      t[0] = f2bf(pa0[s].x); t[1] = f2bf(pa0[s].y); t[2] = f2bf(pa0[s].z); t[3] = f2bf(pa0[s].w);
      t[4] = f2bf(pa1[s].x); t[5] = f2bf(pa1[s].y); t[6] = f2bf(pa1[s].z); t[7] = f2bf(pa1[s].w);
      *(bf16x8*)&As[s][sr * 40 + sk] = t;
    } else {
      bf16x4 t;
      t[0] = f2bf(pa0[s].x); t[1] = f2bf(pa0[s].y); t[2] = f2bf(pa0[s].z); t[3] = f2bf(pa0[s].w);
      *(bf16x4*)&As[s][sr * 40 + sk] = t;
    }
    short* wd = &Ws[s][tid * 40];
    *(bf16x8*)(wd + 0) = pw[s][0];
    *(bf16x8*)(wd + 8) = pw[s][1];
    *(bf16x8*)(wd + 16) = pw[s][2];
    *(bf16x8*)(wd + 24) = pw[s][3];
  };
  auto compute = [&](int s) {
    bf16x8 af[IT], bfr[4];
#pragma unroll
    for (int i = 0; i < IT; i++)
      af[i] = *(const bf16x8*)&As[s][(i * 16 + l16) * 40 + quad * 8];
#pragma unroll
    for (int j = 0; j < 4; j++)
      bfr[j] = *(const bf16x8*)&Ws[s][(wave * 64 + j * 16 + l16) * 40 + quad * 8];
#pragma unroll
    for (int i = 0; i < IT; i++)
#pragma unroll
      for (int j = 0; j < 4; j++)
        acc[i][j] = __builtin_amdgcn_mfma_f32_16x16x32_bf16(af[i], bfr[j], acc[i][j], 0, 0, 0);
  };

  loadA(0, 0); loadW(0, 0);
  loadA(1, 1); loadW(1, 1);
  for (int it = 0; it < KT; it += 2) {
    stage(0);
    stage(1);
    __syncthreads();  // one join per K-tile PAIR (was two)
    if (it + 2 < KT) { loadA(0, it + 2); loadW(0, it + 2); }
    if (it + 3 < KT) { loadA(1, it + 3); loadW(1, it + 3); }
    compute(0);
    compute(1);
    __syncthreads();  // LDS halves free for next pair's stage
  }

  // ---- epilogues ----
  if constexpr (MODE == 4) {
    short* base = (short*)Cv;
#pragma unroll
    for (int i = 0; i < IT; i++)
#pragma unroll
      for (int r = 0; r < 4; r++) {
        const int m = mb * MT + i * 16 + quad * 4 + r;
        if (m >= M) continue;
        const int b = m / NQc, q = m - b * NQc;
#pragma unroll
        for (int j = 0; j < 4; j++) {
          const int cl = wave * 64 + j * 16 + l16;
          const float v = acc[i][j][r] + bias[bn * 256 + cl];
          const int h = cl >> 5, ch = cl & 31;
          if (bn == 0) {
            base[((size_t)(b * 8 + h) * 960 + q) * 32 + ch] =
                f2bf(v * 0.17677669529663687f);
          } else if (bn == 1) {
            base[QKo + ((size_t)(b * 8 + h) * 960 + q) * 32 + ch] = f2bf(v);
          } else {
            base[2 * QKo + ((((size_t)(b * 8 + h) * 15 + (q >> 6)) * 32 + ch) * 64 + (q & 63))] = f2bf(v);
          }
        }
      }
  } else if constexpr (MODE == 0) {
#pragma unroll
    for (int i = 0; i < IT; i++)
#pragma unroll
      for (int j = 0; j < 4; j++) {
        const int cl = wave * 64 + j * 16 + l16;
        const int col = bn * 256 + cl;
        const float bb = bias[col];
#pragma unroll
        for (int r = 0; r < 4; r++) {
          const int m = mb * MT + i * 16 + quad * 4 + r;
          if (m < M) {
            float v = acc[i][j][r] + bb;
            if (ACT == 1) v = fmaxf(v, 0.f);
            ((float*)Cv)[(size_t)m * N + col] = v;
          }
        }
      }
  } else {  // MODE 3: fused LayerNorm epilogue (N==256)
#pragma unroll
    for (int j = 0; j < 4; j++) {
      const int cl = wave * 64 + j * 16 + l16;
      const float bb = bias[cl];
#pragma unroll
      for (int i = 0; i < IT; i++)
#pragma unroll
        for (int r = 0; r < 4; r++) {
          const int m = mb * MT + i * 16 + quad * 4 + r;
          const float rs = (m < M) ? resid[(size_t)m * 256 + cl] : 0.f;
          acc[i][j][r] += bb + rs;
        }
    }
    float2* pr = (float2*)As;
#pragma unroll
    for (int i = 0; i < IT; i++)
#pragma unroll
      for (int r = 0; r < 4; r++) {
        float s = 0.f, q = 0.f;
#pragma unroll
        for (int j = 0; j < 4; j++) {
          s += acc[i][j][r];
          q += acc[i][j][r] * acc[i][j][r];
        }
#pragma unroll
        for (int d = 1; d < 16; d <<= 1) {
          s += __shfl_xor(s, d);
          q += __shfl_xor(q, d);
        }
        if (l16 == 0) pr[(i * 16 + quad * 4 + r) * 4 + wave] = make_float2(s, q);
      }
    __syncthreads();
#pragma unroll
    for (int i = 0; i < IT; i++)
#pragma unroll
      for (int r = 0; r < 4; r++) {
        const int ml = i * 16 + quad * 4 + r;
        float2 p0 = pr[ml * 4 + 0], p1 = pr[ml * 4 + 1];
        float2 p2 = pr[ml * 4 + 2], p3 = pr[ml * 4 + 3];
        const float sum = p0.x + p1.x + p2.x + p3.x;
        const float sq = p0.y + p1.y + p2.y + p3.y;
        const float mean = sum * (1.f / 256.f);
        const float var = sq * (1.f / 256.f) - mean * mean;
        const float rstd = rsqrtf(var + 1e-5f);
        const int m = mb * MT + ml;
        if (m < M) {
#pragma unroll
          for (int j = 0; j < 4; j++) {
            const int cl = wave * 64 + j * 16 + l16;
            const float o = (acc[i][j][r] - mean) * rstd * g[cl] + beta[cl];
            ((float*)Cv)[(size_t)m * 256 + cl] = o;
            if (out2) out2[(size_t)m * 256 + cl] = o + qpos[(size_t)m * 256 + cl];
          }
        }
      }
  }
}

// ---------------------------------------------------------------------------
// Value projection GEMM, v6 (round-6 verified best: 52.4 us): full-N blocks,
// A and B read once at every cache level. A via global_load_lds with
// pre-swizzled source + XOR read; B direct global->reg distance-1 dbuf.
// One block per 64-row tile (grid 1360 = M/64 exact).
__global__ __launch_bounds__(256, 3) void gemm_val_k(
    const float* __restrict__ A, const short* __restrict__ Wt,
    const float* __restrict__ bias, short* __restrict__ Cv, int M,
    const unsigned char* __restrict__ rowmask) {
  __shared__ float As[2][64 * 32];  // 16 KB
  const int mb = blockIdx.x;
  const int tid = threadIdx.x;
  const int lane = tid & 63, wave = tid >> 6;
  const int l16 = lane & 15, quad = lane >> 4;

  // B fragment: col = wave*64 + j*16 + l16, k-tile it, sub-k quad*8
  const short* wp = Wt + (size_t)(wave * 64 + l16) * 32 + quad * 8;

  // A staging source (pre-swizzled chunk so linear DMA + XOR read = identity)
  const int srow = lane >> 3;
  const int schunk = ((lane & 7) ^ srow) * 4;  // swizzled k-chunk (floats)
  const float* abase = A + (size_t)(mb * 64 + wave * 8 + srow) * 256 + schunk;

  f32x4 acc[4][4] = {};
  bf16x8 pb[2][4];

  auto stage = [&](int buf, int it) {
#pragma unroll
    for (int call = 0; call < 2; ++call) {
      const float* src = abase + (size_t)call * (32 * 256) + it * 32;
      float* dst = &As[buf][(call * 32 + wave * 8) * 32];
      __builtin_amdgcn_global_load_lds(
          (const __attribute__((address_space(1))) void*)src,
          (__attribute__((address_space(3))) void*)dst, 16, 0, 0);
    }
  };
  auto loadB = [&](int s, int it) {
#pragma unroll
    for (int j = 0; j < 4; j++)
      pb[s][j] = *(const bf16x8*)(wp + (size_t)(it * 256 + j * 16) * 32);
  };
  auto compute = [&](int cur) {
    bf16x8 af[4];
#pragma unroll
    for (int i = 0; i < 4; i++) {
      const int row = i * 16 + l16;
      const int cb = row & 7;
      const float4 a0 =
          *(const float4*)&As[cur][row * 32 + (((quad * 2) ^ cb) << 2)];
      const float4 a1 =
          *(const float4*)&As[cur][row * 32 + (((quad * 2 + 1) ^ cb) << 2)];
      af[i][0] = f2bf(a0.x); af[i][1] = f2bf(a0.y);
      af[i][2] = f2bf(a0.z); af[i][3] = f2bf(a0.w);
      af[i][4] = f2bf(a1.x); af[i][5] = f2bf(a1.y);
      af[i][6] = f2bf(a1.z); af[i][7] = f2bf(a1.w);
    }
#pragma unroll
    for (int i = 0; i < 4; i++)
#pragma unroll
      for (int j = 0; j < 4; j++)
        acc[i][j] = __builtin_amdgcn_mfma_f32_16x16x32_bf16(af[i], pb[cur][j],
                                                            acc[i][j], 0, 0, 0);
  };

  stage(0, 0);
  loadB(0, 0);
  __syncthreads();  // As[0] + pb[0] ready
  for (int it = 0; it < 8; ++it) {
    const int cur = it & 1;
    if (it + 1 < 8) { stage(cur ^ 1, it + 1); loadB(cur ^ 1, it + 1); }
    compute(cur);     // ds_read + MFMA while next-tile loads fly
    __syncthreads();  // drains stage/loadB(it+1); all waves done with As[cur]
  }

  float bb[4];
#pragma unroll
  for (int j = 0; j < 4; j++) bb[j] = bias[wave * 64 + j * 16 + l16];
#pragma unroll
  for (int i = 0; i < 4; i++)
#pragma unroll
    for (int r = 0; r < 4; r++) {
      const int m = mb * 64 + i * 16 + quad * 4 + r;
      const bool mk = rowmask[m] != 0;
#pragma unroll
      for (int j = 0; j < 4; j++) {
        const int cl = wave * 64 + j * 16 + l16;
        float v = acc[i][j][r] + bb[j];
        if (mk) v = 0.f;
        Cv[(size_t)m * 256 + cl] = f2bf(v);
      }
    }
}

// ---------------------------------------------------------------------------
// Exact fp32 GEMM body (off/aw: sampler-amplified precision path).
// Distance-1 register prefetch (round-9): k0+16 loads fly under the FMA unroll.
DEV void gemm32_body(const float* __restrict__ A, const float* __restrict__ W,
                     const float* __restrict__ bias, float* __restrict__ C,
                     int M, int N, int K, int bid) {
  __shared__ float Asf[16][64];
  __shared__ float Bsf[16][68];
  const int nb = N >> 6;
  const int bm = bid / nb, bn = bid % nb;
  const int tid = threadIdx.x;
  const int tm = tid >> 4, tn = tid & 15;
  const int am = tid >> 2, akk = (tid & 3) * 4;   // A stage coords
  const int bkk = tid >> 4, bn4 = (tid & 15) * 4; // B stage coords
  const int arow = bm * 64 + am;
  float acc[4][4] = {};

  float4 pa, pb;
  auto loadA = [&](int k0) {
    pa = (arow < M) ? *(const float4*)(A + (size_t)arow * K + k0 + akk)
                    : make_float4(0.f, 0.f, 0.f, 0.f);
  };
  auto loadB = [&](int k0) {
    pb = *(const float4*)(W + (size_t)(k0 + bkk) * N + bn * 64 + bn4);
  };

  loadA(0); loadB(0);
  for (int k0 = 0; k0 < K; k0 += 16) {
    Asf[akk + 0][am] = pa.x; Asf[akk + 1][am] = pa.y;
    Asf[akk + 2][am] = pa.z; Asf[akk + 3][am] = pa.w;
    *(float4*)&Bsf[bkk][bn4] = pb;
    __syncthreads();
    if (k0 + 16 < K) { loadA(k0 + 16); loadB(k0 + 16); }  // prefetch in flight
#pragma unroll
    for (int kk = 0; kk < 16; kk++) {
      float a[4], b[4];
#pragma unroll
      for (int i = 0; i < 4; i++) a[i] = Asf[kk][tm * 4 + i];
#pragma unroll
      for (int j = 0; j < 4; j++) b[j] = Bsf[kk][tn * 4 + j];
#pragma unroll
      for (int i = 0; i < 4; i++)
#pragma unroll
        for (int j = 0; j < 4; j++) acc[i][j] = fmaf(a[i], b[j], acc[i][j]);
    }
    __syncthreads();
  }
#pragma unroll
  for (int i = 0; i < 4; i++) {
    const int row = bm * 64 + tm * 4 + i;
    if (row >= M) continue;
#pragma unroll
    for (int j = 0; j < 4; j++) {
      const int col = bn * 64 + tn * 4 + j;
      C[(size_t)row * N + col] = acc[i][j] + bias[col];
    }
  }
}

__global__ __launch_bounds__(256) void gemm32_offaw_k(
    const float* __restrict__ query, const float* __restrict__ off_w,
    const float* __restrict__ off_b, float* __restrict__ offb,
    const float* __restrict__ aw_w, const float* __restrict__ aw_b,
    float* __restrict__ awlin) {
  if (blockIdx.x < 228)
    gemm32_body(query, off_w, off_b, offb, M1, 256, 256, blockIdx.x);
  else
    gemm32_body(query, aw_w, aw_b, awlin, M1, 128, 256, blockIdx.x - 228);
}

// ---------------------------------------------------------------------------
// Flash attention from pre-packed bf16 buffers. Block = (b,h,16 queries),
// 2 waves split key tiles even/odd. Hot loop: coalesced bf16x8 global loads
// (Q,K from [bh][960][32], V^T from [bh][15][32][64]) straight into MFMA —
// no f2bf, no V staging, no barriers. Single merge barrier at end.
__global__ __launch_bounds__(128) void attn_k(const short* __restrict__ qbf,
                                              const short* __restrict__ kbf,
                                              const short* __restrict__ vtbf,
                                              float* __restrict__ sa) {
  __shared__ short Pb[2][16 * 72];
  __shared__ float Om[2][16][32];
  __shared__ float Ml[2][16][2];
  const int bid = blockIdx.x;
  const int qt = bid % QT16, bh = bid / QT16;
  const int tid = threadIdx.x, lane = tid & 63, wave = tid >> 6;
  const int l16 = lane & 15, quad = lane >> 4;

  const int q_local = min(qt * 16 + l16, NQc - 1);
  const bf16x8 qf = *(const bf16x8*)&qbf[((size_t)bh * 960 + q_local) * 32 + quad * 8];
  const short* kb = kbf + (size_t)bh * 960 * 32;
  const short* vb = vtbf + (size_t)bh * 15 * 32 * 64;

  f32x4 o0 = {}, o1 = {};
  float mrun[4] = {-1e30f, -1e30f, -1e30f, -1e30f};
  float lrun[4] = {0.f, 0.f, 0.f, 0.f};
  short* pw = Pb[wave];

  for (int kt = wave; kt < NQT; kt += 2) {
    const int k0 = kt * 64;
    f32x4 s[4];
#pragma unroll
    for (int st = 0; st < 4; st++) {
      const int key = k0 + st * 16 + l16;
      const bf16x8 kf = *(const bf16x8*)&kb[(size_t)key * 32 + quad * 8];
      f32x4 z = {};
      s[st] = __builtin_amdgcn_mfma_f32_16x16x32_bf16(qf, kf, z, 0, 0, 0);
      if (key >= NQc) { s[st][0] = -1e30f; s[st][1] = -1e30f; s[st][2] = -1e30f; s[st][3] = -1e30f; }
    }
    float mnew[4], alpha[4];
#pragma unroll
    for (int r = 0; r < 4; r++) {
      float mx = fmaxf(fmaxf(s[0][r], s[1][r]), fmaxf(s[2][r], s[3][r]));
#pragma unroll
      for (int d = 1; d < 16; d <<= 1) mx = fmaxf(mx, __shfl_xor(mx, d));
      mnew[r] = fmaxf(mrun[r], mx);
      alpha[r] = __expf(mrun[r] - mnew[r]);
      mrun[r] = mnew[r];
    }
    float tsum[4] = {0.f, 0.f, 0.f, 0.f};
#pragma unroll
    for (int st = 0; st < 4; st++)
#pragma unroll
      for (int r = 0; r < 4; r++) {
        float p = __expf(s[st][r] - mnew[r]);
        s[st][r] = p;
        tsum[r] += p;
      }
#pragma unroll
    for (int r = 0; r < 4; r++) {
      float t = tsum[r];
#pragma unroll
      for (int d = 1; d < 16; d <<= 1) t += __shfl_xor(t, d);
      lrun[r] = lrun[r] * alpha[r] + t;
      o0[r] *= alpha[r];
      o1[r] *= alpha[r];
    }
    // P: C-layout -> A-layout via per-wave LDS (wave-local, no barrier)
#pragma unroll
    for (int st = 0; st < 4; st++)
#pragma unroll
      for (int r = 0; r < 4; r++)
        pw[(quad * 4 + r) * 72 + st * 16 + l16] = f2bf(s[st][r]);
    const short* vt = vb + kt * (32 * 64);
#pragma unroll
    for (int c = 0; c < 2; c++) {
      bf16x8 pf = *(const bf16x8*)&pw[l16 * 72 + c * 32 + quad * 8];
      bf16x8 vf0 = *(const bf16x8*)&vt[(size_t)l16 * 64 + c * 32 + quad * 8];
      bf16x8 vf1 = *(const bf16x8*)&vt[(size_t)(16 + l16) * 64 + c * 32 + quad * 8];
      o0 = __builtin_amdgcn_mfma_f32_16x16x32_bf16(pf, vf0, o0, 0, 0, 0);
      o1 = __builtin_amdgcn_mfma_f32_16x16x32_bf16(pf, vf1, o1, 0, 0, 0);
    }
  }
#pragma unroll
  for (int r = 0; r < 4; r++) {
    Om[wave][quad * 4 + r][l16] = o0[r];
    Om[wave][quad * 4 + r][16 + l16] = o1[r];
  }
  if (l16 == 0) {
#pragma unroll
    for (int r = 0; r < 4; r++) {
      Ml[wave][quad * 4 + r][0] = mrun[r];
      Ml[wave][quad * 4 + r][1] = lrun[r];
    }
  }
  __syncthreads();
  {
    const int q = tid >> 3;
    const int c4 = (tid & 7) * 4;
    const float m0 = Ml[0][q][0], m1 = Ml[1][q][0];
    const float M = fmaxf(m0, m1);
    const float a0 = __expf(m0 - M), a1 = __expf(m1 - M);
    const float lsum = a0 * Ml[0][q][1] + a1 * Ml[1][q][1];
    const int qg = qt * 16 + q;
    if (qg < NQc) {
      const float inv = 1.f / lsum;
      float4 o;
      o.x = (a0 * Om[0][q][c4 + 0] + a1 * Om[1][q][c4 + 0]) * inv;
      o.y = (a0 * Om[0][q][c4 + 1] + a1 * Om[1][q][c4 + 1]) * inv;
      o.z = (a0 * Om[0][q][c4 + 2] + a1 * Om[1][q][c4 + 2]) * inv;
      o.w = (a0 * Om[0][q][c4 + 3] + a1 * Om[1][q][c4 + 3]) * inv;
      const int b = bh >> 3, h = bh & 7;
      *(float4*)&sa[(size_t)(b * NQc + qg) * 256 + h * 32 + c4] = o;
    }
  }
}

// ---------------------------------------------------------------------------
__global__ __launch_bounds__(256) void sample_k(
    const float* __restrict__ awlin, const float* __restrict__ off,
    const float* __restrict__ refp, const short* __restrict__ value,
    float* __restrict__ accout) {
  const int wid = blockIdx.x * 4 + (threadIdx.x >> 6);
  const int lane = threadIdx.x & 63;
  const int bq = wid >> 3, h = wid & 7;
  const int b = bq / NQc;
  const int l16 = lane & 15;

  float wraw = awlin[(size_t)bq * 128 + h * 16 + l16];
  float mx = wraw;
#pragma unroll
  for (int d = 1; d < 16; d <<= 1) mx = fmaxf(mx, __shfl_xor(mx, d));
  float e = __expf(wraw - mx), ssum = e;
#pragma unroll
  for (int d = 1; d < 16; d <<= 1) ssum += __shfl_xor(ssum, d);
  const float wnorm = e / ssum;

  const int ch = lane & 31, sub = lane >> 5;
  float facc = 0.f;
#pragma unroll
  for (int it = 0; it < 8; it++) {
    const int pt = it * 2 + sub;
    const float w = __shfl(wnorm, pt);
    const int l = pt >> 2;
    const int W = 128 >> l;
    const int start = (l == 0) ? 0 : (l == 1) ? 16384 : (l == 2) ? 20480 : 21504;
    const float offx = off[(size_t)bq * 256 + h * 32 + pt * 2];
    const float offy = off[(size_t)bq * 256 + h * 32 + pt * 2 + 1];
    const float rx = refp[(size_t)bq * 8 + l * 2];
    const float ry = refp[(size_t)bq * 8 + l * 2 + 1];
    const float x = rx * (float)W + offx - 0.5f;
    const float y = ry * (float)W + offy - 0.5f;
    const float x0f = floorf(x), y0f = floorf(y);
    const float wx = x - x0f, wy = y - y0f;
    const int x0 = (int)x0f, y0 = (int)y0f;
    const short* vbp = value + ((size_t)b * Sc + start) * 256 + h * 32 + ch;
#pragma unroll
    for (int c4 = 0; c4 < 4; c4++) {
      const int dx = c4 & 1, dy = c4 >> 1;
      const int xi = x0 + dx, yi = y0 + dy;
      const bool valid = (xi >= 0) && (xi < W) && (yi >= 0) && (yi < W);
      const int xc = min(max(xi, 0), W - 1);
      const int yc = min(max(yi, 0), W - 1);
      const float gvv = bf2f(vbp[(size_t)(yc * W + xc) * 256]);
      const float ww = (dx ? wx : 1.f - wx) * (dy ? wy : 1.f - wy);
      facc += valid ? w * ww * gvv : 0.f;
    }
  }
  facc += __shfl_xor(facc, 32);
  if (lane < 32) accout[(size_t)bq * 256 + h * 32 + ch] = facc;
}

// ---------------------------------------------------------------------------
extern "C" void kernel_launch(void* const* d_in, const int* in_sizes, int n_in,
                              void* d_out, int out_size, void* d_ws,
                              size_t ws_size, hipStream_t stream) {
  const float* tgt = (const float*)d_in[0];
  const float* query_pos = (const float*)d_in[1];
  const float* refp = (const float*)d_in[2];
  const float* memory = (const float*)d_in[3];
  const float* in_proj_w = (const float*)d_in[4];
  const float* in_proj_b = (const float*)d_in[5];
  const float* out_proj_w = (const float*)d_in[6];
  const float* out_proj_b = (const float*)d_in[7];
  const float* ln1_g = (const float*)d_in[8];
  const float* ln1_b = (const float*)d_in[9];
  const float* ln2_g = (const float*)d_in[10];
  const float* ln2_b = (const float*)d_in[11];
  const float* ln3_g = (const float*)d_in[12];
  const float* ln3_b = (const float*)d_in[13];
  const float* vproj_w = (const float*)d_in[14];
  const float* vproj_b = (const float*)d_in[15];
  const float* off_w = (const float*)d_in[16];
  const float* off_b = (const float*)d_in[17];
  const float* aw_w = (const float*)d_in[18];
  const float* aw_b = (const float*)d_in[19];
  const float* oproj_w = (const float*)d_in[20];
  const float* oproj_b = (const float*)d_in[21];
  const float* lin1_w = (const float*)d_in[22];
  const float* lin1_b = (const float*)d_in[23];
  const float* lin2_w = (const float*)d_in[24];
  const float* lin2_b = (const float*)d_in[25];
  const unsigned char* mem_mask = (const unsigned char*)d_in[27];
  float* out = (float*)d_out;

  float* ws = (float*)d_ws;
  short* qbf = (short*)(ws + 921600);  // qbf|kbf|vtbf: 3*983040 shorts
  float* sa = ws + 3686400;
  float* tgt2 = ws + 5529600;
  float* query = ws + 6451200;
  float* offb = ws + 7372800;
  float* awlin = ws + 8294400;
  float* accb = ws + 8755200;
  float* tgt3 = ws + 9676800;
  float* ff1 = ws + 10598400;     // [3600][1024]
  short* valueBf = (short*)(ws + 14284800);  // 22282240 shorts
  short* wbase = valueBf + 22282240;
  short* inT = wbase + 0;         // [8][768][32]
  short* outT = wbase + 196608;
  short* vT = wbase + 262144;
  short* oT = wbase + 327680;
  short* lin1T = wbase + 393216;  // [8][1024][32]
  short* lin2T = wbase + 655360;  // [32][256][32]

  pack_all_k<<<896, 256, 0, stream>>>(in_proj_w, inT, out_proj_w, outT,
                                      vproj_w, vT, oproj_w, oT,
                                      lin1_w, lin1T, lin2_w, lin2T);

  // fused q|k|v projection -> bf16 MFMA-layout buffers
  gemmv_k<4, 0, 32><<<113 * 3, 256, 0, stream>>>(
      tgt, query_pos, inT, in_proj_b, qbf, nullptr, M1, 768, 256,
      nullptr, nullptr, nullptr, nullptr, nullptr, nullptr);
  attn_k<<<Bc * Hc * QT16, 128, 0, stream>>>(qbf, qbf + QKo, qbf + 2 * QKo, sa);
  // out_proj + residual + LN2, and query = tgt2 + query_pos
  gemmv_k<3, 0, 32><<<113, 256, 0, stream>>>(
      sa, nullptr, outT, out_proj_b, tgt2, nullptr, M1, 256, 256,
      nullptr, ln2_g, ln2_b, tgt, query_pos, query);
  // value = memory @ vproj -> bf16 (full-N once-per-cache-level v6)
  gemm_val_k<<<1360, 256, 0, stream>>>(memory, vT, vproj_b, valueBf, Bc * Sc, mem_mask);
  // off + aw (exact fp32, distance-1 prefetch)
  gemm32_offaw_k<<<342, 256, 0, stream>>>(query, off_w, off_b, offb, aw_w, aw_b, awlin);
  sample_k<<<Bc * NQc * Hc / 4, 256, 0, stream>>>(awlin, offb, refp, valueBf, accb);
  // oproj + residual + LN1
  gemmv_k<3, 0, 32><<<113, 256, 0, stream>>>(
      accb, nullptr, oT, oproj_b, tgt3, nullptr, M1, 256, 256,
      nullptr, ln1_g, ln1_b, tgt2, nullptr, nullptr);
  // FFN
  gemmv_k<0, 1, 64><<<57 * 4, 256, 0, stream>>>(
      tgt3, nullptr, lin1T, lin1_b, ff1, nullptr, M1, 1024, 256,
      nullptr, nullptr, nullptr, nullptr, nullptr, nullptr);
  gemmv_k<3, 0, 32><<<113, 256, 0, stream>>>(
      ff1, nullptr, lin2T, lin2_b, out, nullptr, M1, 256, 1024,
      nullptr, ln3_g, ln3_b, tgt3, nullptr, nullptr);
}